// Round 6
// baseline (609.662 us; speedup 1.0000x reference)
//
#include <hip/hip_runtime.h>
#include <hip/hip_bf16.h>

#define M_SAMPLES 524288
#define NRAYS 8192
#define GXD 160
#define GYD 160
#define GZD 128
#define GYZ (GYD*GZD)
#define NVOX (GXD*GYD*GZD)
#define ACT_SHIFT -13.81550955796f
#define ROWA 136      // hA leading dim (shorts)
#define ROWB 168      // hB leading dim (shorts)

typedef __bf16 bf16x8 __attribute__((ext_vector_type(8)));
typedef float f32x4 __attribute__((ext_vector_type(4)));
typedef float f32x16 __attribute__((ext_vector_type(16)));

static __device__ inline unsigned short f2bf(float f){
  __hip_bfloat16 h = __float2bfloat16(f);
  unsigned short u; __builtin_memcpy(&u, &h, 2); return u;
}
static __device__ inline float flo(unsigned int u){ return __uint_as_float(u << 16); }
static __device__ inline float fhi(unsigned int u){ return __uint_as_float(u & 0xffff0000u); }

#if defined(__has_builtin)
#if __has_builtin(__builtin_amdgcn_cvt_pk_bf16_f32)
#define HAVE_PK_BF16 1
#endif
#endif

static __device__ inline unsigned int packbf(float a, float b){
#ifdef HAVE_PK_BF16
  typedef __bf16 bf16v2 __attribute__((ext_vector_type(2)));
  bf16v2 r = __builtin_amdgcn_cvt_pk_bf16_f32(a, b);
  unsigned int u; __builtin_memcpy(&u, &r, 4); return u;
#else
  return (unsigned int)f2bf(a) | ((unsigned int)f2bf(b) << 16);
#endif
}

struct Tri {
  int ix, iy, iz;
  float wx0, wx1, wy0, wy1, wz0, wz1;
};
static __device__ inline Tri tri_setup(float x, float y, float z){
  Tri t;
  float tx = (x+1.f)*0.5f*(float)(GXD-1); tx = fminf(fmaxf(tx,0.f),(float)(GXD-1));
  float ty = (y+1.f)*0.5f*(float)(GYD-1); ty = fminf(fmaxf(ty,0.f),(float)(GYD-1));
  float tz = (z+1.f)*0.5f*(float)(GZD-1); tz = fminf(fmaxf(tz,0.f),(float)(GZD-1));
  t.ix = min((int)tx, GXD-2); t.iy = min((int)ty, GYD-2); t.iz = min((int)tz, GZD-2);
  float fx = tx-t.ix, fy = ty-t.iy, fz = tz-t.iz;
  t.wx0 = 1.f-fx; t.wx1 = fx; t.wy0 = 1.f-fy; t.wy1 = fy; t.wz0 = 1.f-fz; t.wz1 = fz;
  return t;
}

// ---------------- mask dtype detection (numpy bool bytes vs int32) -------------
__global__ void k_detect(const unsigned int* __restrict__ mw, int* __restrict__ flag){
  if(threadIdx.x == 0){
    int f = 0;
    for(int i = 0; i < 64; ++i) if(mw[i] > 1u) f = 1;
    *flag = f;   // 1 = byte format, 0 = int32 format
  }
}

// ---------------- weight transpose + bf16 convert ------------------------------
__global__ __launch_bounds__(256) void k_prep_w(const float* __restrict__ W0,
    const float* __restrict__ W1, const float* __restrict__ W2,
    const float* __restrict__ Wr,
    unsigned short* __restrict__ wt0, unsigned short* __restrict__ wt1,
    unsigned short* __restrict__ wt2, unsigned short* __restrict__ wtr)
{
  int t = blockIdx.x*256 + threadIdx.x;
  if(t < 128*96){
    int n = t/96, k = t%96;
    wt0[t] = f2bf((k < 75) ? W0[k*128 + n] : 0.f);
  } else if(t < 128*96 + 16384){
    int j = t - 128*96; int n = j/128, k = j%128;
    wt1[j] = f2bf(W1[k*128 + n]);
  } else if(t < 128*96 + 32768){
    int j = t - 128*96 - 16384; int n = j/128, k = j%128;
    wt2[j] = f2bf(W2[k*128 + n]);
  } else if(t < 128*96 + 32768 + 16*160){
    int j = t - 128*96 - 32768; int n = j/160, k = j%160;
    wtr[j] = f2bf((n < 3 && k < 155) ? Wr[k*3 + n] : 0.f);
  }
}

// ---------------- per-ray view-dir positional embedding ------------------------
__global__ __launch_bounds__(256) void k_viewemb(const float* __restrict__ vd,
                                                 float* __restrict__ ve)
{
  int t = blockIdx.x*256 + threadIdx.x;
  if(t >= NRAYS*27) return;
  int ray = t/27, c = t%27;
  float v;
  if(c < 3) v = vd[ray*3 + c];
  else if(c < 15){
    int q = c - 3; int ci = q/4, p = q%4;
    v = sinf(vd[ray*3 + ci] * (float)(1 << p));
  } else {
    int q = c - 15; int ci = q/4, p = q%4;
    v = cosf(vd[ray*3 + ci] * (float)(1 << p));
  }
  ve[t] = v;
}

// ---------------- voxel repack: 12 bf16 feats (+pad) = 32 B/voxel --------------
__global__ __launch_bounds__(256) void k_repack(const float* __restrict__ k0,
                                                uint4* __restrict__ packed)
{
  int v = blockIdx.x*256 + threadIdx.x;
  if(v >= NVOX) return;
  const float4* kp = (const float4*)(k0 + (size_t)v*12);
  float4 a = kp[0], b = kp[1], c = kp[2];
  uint4 o0, o1;
  o0.x = packbf(a.x, a.y); o0.y = packbf(a.z, a.w);
  o0.z = packbf(b.x, b.y); o0.w = packbf(b.z, b.w);
  o1.x = packbf(c.x, c.y); o1.y = packbf(c.z, c.w);
  o1.z = 0; o1.w = 0;
  packed[(size_t)v*2]   = o0;
  packed[(size_t)v*2+1] = o1;
}

// ---------------- per-sample alpha: mask + trilinear density -------------------
__global__ __launch_bounds__(256) void k_alpha(const float* __restrict__ xyz,
    const void* __restrict__ mask, const float* __restrict__ density,
    const int* __restrict__ flag, float* __restrict__ alpha_w)
{
  int i = blockIdx.x*256 + threadIdx.x;
  float x = xyz[3*i+0], y = xyz[3*i+1], z = xyz[3*i+2];

  int mx = (int)rintf(x*79.5f + 79.5f); mx = min(max(mx,0), GXD-1);
  int my = (int)rintf(y*79.5f + 79.5f); my = min(max(my,0), GYD-1);
  int mz = (int)rintf(z*63.5f + 63.5f); mz = min(max(mz,0), GZD-1);
  int midx = mx*GYZ + my*GZD + mz;
  bool m = (*flag) ? (((const unsigned char*)mask)[midx] != 0)
                   : (((const int*)mask)[midx] != 0);

  Tri t = tri_setup(x, y, z);
  float wxv[2] = {t.wx0, t.wx1}, wyv[2] = {t.wy0, t.wy1};
  float d = 0.f;
  #pragma unroll
  for(int dx = 0; dx < 2; ++dx)
  #pragma unroll
  for(int dy = 0; dy < 2; ++dy){
    float wxy = wxv[dx]*wyv[dy];
    int vox = (t.ix+dx)*GYZ + (t.iy+dy)*GZD + t.iz;
    d += wxy*(t.wz0*density[vox] + t.wz1*density[vox+1]);
  }
  float e = expf(d + ACT_SHIFT);
  float alpha = 1.f - rsqrtf(1.f + e);   // (1+e)^(-0.5), INTERVAL=0.5
  if(!m) alpha = 0.f;
  alpha_w[i] = alpha;
}

// ---------------- per-ray compositing: one wave per ray, shfl prefix product ---
__global__ __launch_bounds__(256) void k_comp(const int* __restrict__ ray_id,
    float* __restrict__ alpha_w, float* __restrict__ out)
{
  int r = blockIdx.x*4 + (threadIdx.x >> 6);   // grid = NRAYS/4 blocks
  int lane = threadIdx.x & 63;
  int lo = 0, hi = M_SAMPLES;
  while(lo < hi){ int mid = (lo+hi) >> 1; if(ray_id[mid] < r) lo = mid+1; else hi = mid; }
  int s = lo;
  int lo2 = s, hi2 = M_SAMPLES;
  while(lo2 < hi2){ int mid = (lo2+hi2) >> 1; if(ray_id[mid] < r+1) lo2 = mid+1; else hi2 = mid; }
  int e = lo2;

  float carry = 1.f;
  for(int base = s; base < e; base += 64){
    int idx = base + lane;
    float a = (idx < e) ? alpha_w[idx] : 0.f;
    float incl = 1.f - a;
    #pragma unroll
    for(int d2 = 1; d2 < 64; d2 <<= 1){
      float t = __shfl_up(incl, d2);
      if(lane >= d2) incl *= t;
    }
    float excl = __shfl_up(incl, 1);
    if(lane == 0) excl = 1.f;
    if(idx < e) alpha_w[idx] = carry * excl * a;   // weight, in place
    carry *= __shfl(incl, 63);
  }
  if(lane == 0){ out[3*r+0] = carry; out[3*r+1] = carry; out[3*r+2] = carry; }
}

// ---------------- fused MLP (feature gather + 3 layers + head + composite) -----
// 32x32x16 MFMA with A=weights, B=activations -> D[neuron][sample]
template<int KDIM, int SROW, int DROW>
static __device__ inline void layer32(const unsigned short* src, unsigned short* dst,
    const unsigned short* __restrict__ wt, const float* __restrict__ bias,
    int wave, int ln, int kh)
{
  constexpr int NS = KDIM/16;
  int tile_s = wave & 1, tile_n = wave >> 1;
  const unsigned short* wbase = wt + (tile_n*32 + ln)*KDIM + kh*8;
  const unsigned short* abase = src + (tile_s*32 + ln)*SROW + kh*8;
  f32x16 acc = {0.f,0.f,0.f,0.f,0.f,0.f,0.f,0.f,0.f,0.f,0.f,0.f,0.f,0.f,0.f,0.f};
  #pragma unroll
  for(int st = 0; st < NS; ++st){
    bf16x8 af = *(const bf16x8*)(wbase + st*16);
    bf16x8 bfr = *(const bf16x8*)(abase + st*16);
    acc = __builtin_amdgcn_mfma_f32_32x32x16_bf16(af, bfr, acc, 0, 0, 0);
  }
  int scol = tile_s*32 + ln;
  #pragma unroll
  for(int g = 0; g < 4; ++g){
    int n0 = tile_n*32 + g*8 + kh*4;
    float4 bv = *(const float4*)(bias + n0);
    unsigned int lo = packbf(fmaxf(acc[4*g+0] + bv.x, 0.f), fmaxf(acc[4*g+1] + bv.y, 0.f));
    unsigned int hi = packbf(fmaxf(acc[4*g+2] + bv.z, 0.f), fmaxf(acc[4*g+3] + bv.w, 0.f));
    unsigned long long o = (unsigned long long)lo | ((unsigned long long)hi << 32);
    *(unsigned long long*)(dst + scol*DROW + n0) = o;
  }
}

template<int PACKED>
__global__ __launch_bounds__(512) void k_mlp(const float* __restrict__ xyz,
    const int* __restrict__ ray_id, const uint4* __restrict__ packed,
    const float* __restrict__ k0, const float* __restrict__ weights,
    const unsigned short* __restrict__ wt0, const unsigned short* __restrict__ wt1,
    const unsigned short* __restrict__ wt2, const unsigned short* __restrict__ wtr,
    const float* __restrict__ b0, const float* __restrict__ b1,
    const float* __restrict__ b2, const float* __restrict__ br,
    const float* __restrict__ ve, float* __restrict__ out)
{
  __shared__ alignas(16) unsigned short hA[64*ROWA];
  __shared__ alignas(16) unsigned short hB[64*ROWB];
  __shared__ float red[64*3];
  __shared__ float w_s[64];
  __shared__ int ray_s[64];

  int tid = threadIdx.x;
  int lane = tid & 63, wave = tid >> 6;
  int i = blockIdx.x*64 + lane;

  // phase 0: wave 0 = trilinear feature gather + cols 0..15; waves 1-5 posemb
  //          chunks; waves 6,7 ve cols + w_s/ray_s
  if(wave == 0){
    float x = xyz[3*i+0], y = xyz[3*i+1], z = xyz[3*i+2];
    Tri t = tri_setup(x, y, z);
    float wxv[2] = {t.wx0, t.wx1}, wyv[2] = {t.wy0, t.wy1};
    float f[12];
    #pragma unroll
    for(int c = 0; c < 12; ++c) f[c] = 0.f;
    if(PACKED){
      #pragma unroll
      for(int dx = 0; dx < 2; ++dx)
      #pragma unroll
      for(int dy = 0; dy < 2; ++dy){
        float wxy = wxv[dx]*wyv[dy];
        float w0 = wxy*t.wz0, w1 = wxy*t.wz1;
        size_t vox = (size_t)((t.ix+dx)*GYZ + (t.iy+dy)*GZD + t.iz);
        const uint4* pv = packed + vox*2;
        uint4 q0 = pv[0], q2 = pv[2], q3 = pv[3];
        uint4 q1 = pv[1];
        f[0]  += w0*flo(q0.x) + w1*flo(q2.x);  f[1]  += w0*fhi(q0.x) + w1*fhi(q2.x);
        f[2]  += w0*flo(q0.y) + w1*flo(q2.y);  f[3]  += w0*fhi(q0.y) + w1*fhi(q2.y);
        f[4]  += w0*flo(q0.z) + w1*flo(q2.z);  f[5]  += w0*fhi(q0.z) + w1*fhi(q2.z);
        f[6]  += w0*flo(q0.w) + w1*flo(q2.w);  f[7]  += w0*fhi(q0.w) + w1*fhi(q2.w);
        f[8]  += w0*flo(q1.x) + w1*flo(q3.x);  f[9]  += w0*fhi(q1.x) + w1*fhi(q3.x);
        f[10] += w0*flo(q1.y) + w1*flo(q3.y);  f[11] += w0*fhi(q1.y) + w1*fhi(q3.y);
      }
    } else {
      #pragma unroll
      for(int dx = 0; dx < 2; ++dx)
      #pragma unroll
      for(int dy = 0; dy < 2; ++dy){
        float wxy = wxv[dx]*wyv[dy];
        float w0 = wxy*t.wz0, w1 = wxy*t.wz1;
        int vox = (t.ix+dx)*GYZ + (t.iy+dy)*GZD + t.iz;
        const float4* v = (const float4*)(k0 + (size_t)vox*12);
        float4 a0 = v[0], a1 = v[1], a2 = v[2];
        float4 c0 = v[3], c1 = v[4], c2 = v[5];
        f[0] += w0*a0.x + w1*c0.x;  f[1] += w0*a0.y + w1*c0.y;
        f[2] += w0*a0.z + w1*c0.z;  f[3] += w0*a0.w + w1*c0.w;
        f[4] += w0*a1.x + w1*c1.x;  f[5] += w0*a1.y + w1*c1.y;
        f[6] += w0*a1.z + w1*c1.z;  f[7] += w0*a1.w + w1*c1.w;
        f[8] += w0*a2.x + w1*c2.x;  f[9] += w0*a2.y + w1*c2.y;
        f[10]+= w0*a2.z + w1*c2.z;  f[11]+= w0*a2.w + w1*c2.w;
      }
    }
    unsigned int d[8];
    #pragma unroll
    for(int j = 0; j < 6; ++j) d[j] = packbf(f[2*j], f[2*j+1]);
    d[6] = packbf(x, y);
    d[7] = packbf(z, __sinf(x));          // col 15 = sin(x * 2^0)
    uint4* p = (uint4*)(hA + lane*ROWA);
    p[0] = make_uint4(d[0],d[1],d[2],d[3]);
    p[1] = make_uint4(d[4],d[5],d[6],d[7]);
  } else if(wave < 6){
    float x = xyz[3*i+0], y = xyz[3*i+1], z = xyz[3*i+2];
    float v[16];
    #pragma unroll
    for(int j = 0; j < 16; ++j){
      int c = wave*16 + j;
      float r;
      if(c >= 75) r = 0.f;
      else {
        int q = (c < 45) ? (c-15) : (c-45);
        int ci = q/10, p = q - ci*10;
        float xv = (ci == 0) ? x : ((ci == 1) ? y : z);
        float a = xv * (float)(1 << p);
        r = (c < 45) ? __sinf(a) : __cosf(a);
      }
      v[j] = r;
    }
    unsigned int d[8];
    #pragma unroll
    for(int j = 0; j < 8; ++j) d[j] = packbf(v[2*j], v[2*j+1]);
    uint4* p = (uint4*)(hA + lane*ROWA + wave*16);
    p[0] = make_uint4(d[0],d[1],d[2],d[3]);
    p[1] = make_uint4(d[4],d[5],d[6],d[7]);
  } else {
    int ray = ray_id[i];
    int base = 128 + (wave-6)*16;
    unsigned int d[8];
    #pragma unroll
    for(int j = 0; j < 8; ++j){
      int c0i = base - 128 + 2*j;
      float a = (c0i     < 27) ? ve[ray*27 + c0i]     : 0.f;
      float b = (c0i + 1 < 27) ? ve[ray*27 + c0i + 1] : 0.f;
      d[j] = packbf(a, b);
    }
    uint4* p = (uint4*)(hB + lane*ROWB + base);
    p[0] = make_uint4(d[0],d[1],d[2],d[3]);
    p[1] = make_uint4(d[4],d[5],d[6],d[7]);
    if(wave == 6){ w_s[lane] = weights[i]; ray_s[lane] = ray; }
  }
  __syncthreads();

  int ln = lane & 31, kh = lane >> 5;
  layer32< 96, ROWA, ROWB>(hA, hB, wt0, b0, wave, ln, kh);  __syncthreads();
  layer32<128, ROWB, ROWA>(hB, hA, wt1, b1, wave, ln, kh);  __syncthreads();
  layer32<128, ROWA, ROWB>(hA, hB, wt2, b2, wave, ln, kh);  __syncthreads();

  // rgb head via 16x16x32 MFMA, K=160 (128 h + 27 ve + 5 pad), waves 0..3
  int col = lane & 15, q = lane >> 4;
  if(wave < 4){
    int mt = wave;
    f32x4 acc = {0.f, 0.f, 0.f, 0.f};
    const unsigned short* arow = hB + (mt*16 + col)*ROWB + q*8;
    const unsigned short* wrow = wtr + col*160 + q*8;
    #pragma unroll
    for(int ks = 0; ks < 5; ++ks){
      bf16x8 af = *(const bf16x8*)(arow + ks*32);
      bf16x8 bfr = *(const bf16x8*)(wrow + ks*32);
      acc = __builtin_amdgcn_mfma_f32_16x16x32_bf16(af, bfr, acc, 0, 0, 0);
    }
    if(col < 3){
      #pragma unroll
      for(int r = 0; r < 4; ++r){
        int sl = mt*16 + q*4 + r;
        float v = acc[r] + br[col];
        float sg = 1.f / (1.f + expf(-v));
        red[sl*3 + col] = w_s[sl] * sg;
      }
    }
  }
  __syncthreads();

  // segmented reduce over sorted ray ids, one atomic per segment
  if(tid < 192){
    int c = tid >> 6, ss = tid & 63;
    int sray = ray_s[ss];
    if(ss == 0 || ray_s[ss-1] != sray){
      float sum = 0.f;
      int j = ss;
      while(j < 64 && ray_s[j] == sray){ sum += red[j*3 + c]; ++j; }
      atomicAdd(&out[sray*3 + c], sum);
    }
  }
}

// ---------------- host ----------------------------------------------------------
extern "C" void kernel_launch(void* const* d_in, const int* in_sizes, int n_in,
                              void* d_out, int out_size, void* d_ws, size_t ws_size,
                              hipStream_t stream)
{
  const float* xyz      = (const float*)d_in[0];
  const int*   ray_id   = (const int*)  d_in[1];
  const float* viewdirs = (const float*)d_in[2];
  const void*  mask     =               d_in[3];
  const float* density  = (const float*)d_in[4];
  const float* k0       = (const float*)d_in[5];
  const float* W0 = (const float*)d_in[6];  const float* b0 = (const float*)d_in[7];
  const float* W1 = (const float*)d_in[8];  const float* b1 = (const float*)d_in[9];
  const float* W2 = (const float*)d_in[10]; const float* b2 = (const float*)d_in[11];
  const float* Wr = (const float*)d_in[12]; const float* br = (const float*)d_in[13];
  float* out = (float*)d_out;

  char* ws = (char*)d_ws;
  size_t off = 0;
  auto take = [&](size_t nbytes) -> void* {
    void* p = ws + off;
    off = (off + nbytes + 255) & ~(size_t)255;
    return p;
  };
  int*            flag    = (int*)           take(4);
  unsigned short* wt0     = (unsigned short*)take(128*96*2);
  unsigned short* wt1     = (unsigned short*)take(128*128*2);
  unsigned short* wt2     = (unsigned short*)take(128*128*2);
  unsigned short* wtr     = (unsigned short*)take(16*160*2);
  float*          ve      = (float*)         take((size_t)NRAYS*27*4);
  float*          alpha_w = (float*)         take((size_t)M_SAMPLES*4);
  uint4*          packed  = (uint4*)         take((size_t)NVOX*32);
  bool use_packed = (ws_size >= off);

  k_detect <<<1,   64,  0, stream>>>((const unsigned int*)mask, flag);
  k_prep_w <<<186, 256, 0, stream>>>(W0, W1, W2, Wr, wt0, wt1, wt2, wtr);
  k_viewemb<<<864, 256, 0, stream>>>(viewdirs, ve);
  k_alpha  <<<M_SAMPLES/256, 256, 0, stream>>>(xyz, mask, density, flag, alpha_w);
  k_comp   <<<NRAYS/4, 256, 0, stream>>>(ray_id, alpha_w, out);
  if(use_packed){
    k_repack<<<(NVOX+255)/256, 256, 0, stream>>>(k0, packed);
    k_mlp<1><<<M_SAMPLES/64, 512, 0, stream>>>(xyz, ray_id, packed, k0, alpha_w,
                                               wt0, wt1, wt2, wtr, b0, b1, b2, br, ve, out);
  } else {
    k_mlp<0><<<M_SAMPLES/64, 512, 0, stream>>>(xyz, ray_id, (const uint4*)k0, k0, alpha_w,
                                               wt0, wt1, wt2, wtr, b0, b1, b2, br, ve, out);
  }
}

// Round 7
// 521.262 us; speedup vs baseline: 1.1696x; 1.1696x over previous
//
#include <hip/hip_runtime.h>
#include <hip/hip_bf16.h>

#define M_SAMPLES 524288
#define NRAYS 8192
#define GXD 160
#define GYD 160
#define GZD 128
#define GYZ (GYD*GZD)
#define NVOX (GXD*GYD*GZD)
#define ACT_SHIFT -13.81550955796f
#define ROWA 136      // hA leading dim (shorts)
#define ROWB 168      // hB leading dim (shorts)

typedef __bf16 bf16x8 __attribute__((ext_vector_type(8)));
typedef float f32x4 __attribute__((ext_vector_type(4)));
typedef float f32x16 __attribute__((ext_vector_type(16)));

static __device__ inline unsigned short f2bf(float f){
  __hip_bfloat16 h = __float2bfloat16(f);
  unsigned short u; __builtin_memcpy(&u, &h, 2); return u;
}
static __device__ inline float flo(unsigned int u){ return __uint_as_float(u << 16); }
static __device__ inline float fhi(unsigned int u){ return __uint_as_float(u & 0xffff0000u); }

#if defined(__has_builtin)
#if __has_builtin(__builtin_amdgcn_cvt_pk_bf16_f32)
#define HAVE_PK_BF16 1
#endif
#endif

static __device__ inline unsigned int packbf(float a, float b){
#ifdef HAVE_PK_BF16
  typedef __bf16 bf16v2 __attribute__((ext_vector_type(2)));
  bf16v2 r = __builtin_amdgcn_cvt_pk_bf16_f32(a, b);
  unsigned int u; __builtin_memcpy(&u, &r, 4); return u;
#else
  return (unsigned int)f2bf(a) | ((unsigned int)f2bf(b) << 16);
#endif
}

struct Tri {
  int ix, iy, iz;
  float wx0, wx1, wy0, wy1, wz0, wz1;
};
static __device__ inline Tri tri_setup(float x, float y, float z){
  Tri t;
  float tx = (x+1.f)*0.5f*(float)(GXD-1); tx = fminf(fmaxf(tx,0.f),(float)(GXD-1));
  float ty = (y+1.f)*0.5f*(float)(GYD-1); ty = fminf(fmaxf(ty,0.f),(float)(GYD-1));
  float tz = (z+1.f)*0.5f*(float)(GZD-1); tz = fminf(fmaxf(tz,0.f),(float)(GZD-1));
  t.ix = min((int)tx, GXD-2); t.iy = min((int)ty, GYD-2); t.iz = min((int)tz, GZD-2);
  float fx = tx-t.ix, fy = ty-t.iy, fz = tz-t.iz;
  t.wx0 = 1.f-fx; t.wx1 = fx; t.wy0 = 1.f-fy; t.wy1 = fy; t.wz0 = 1.f-fz; t.wz1 = fz;
  return t;
}

// ---------------- mask dtype detection (numpy bool bytes vs int32) -------------
__global__ void k_detect(const unsigned int* __restrict__ mw, int* __restrict__ flag){
  if(threadIdx.x == 0){
    int f = 0;
    for(int i = 0; i < 64; ++i) if(mw[i] > 1u) f = 1;
    *flag = f;   // 1 = byte format, 0 = int32 format
  }
}

// ---------------- weight transpose + bf16 convert ------------------------------
__global__ __launch_bounds__(256) void k_prep_w(const float* __restrict__ W0,
    const float* __restrict__ W1, const float* __restrict__ W2,
    const float* __restrict__ Wr,
    unsigned short* __restrict__ wt0, unsigned short* __restrict__ wt1,
    unsigned short* __restrict__ wt2, unsigned short* __restrict__ wtr)
{
  int t = blockIdx.x*256 + threadIdx.x;
  if(t < 128*96){
    int n = t/96, k = t%96;
    wt0[t] = f2bf((k < 75) ? W0[k*128 + n] : 0.f);
  } else if(t < 128*96 + 16384){
    int j = t - 128*96; int n = j/128, k = j%128;
    wt1[j] = f2bf(W1[k*128 + n]);
  } else if(t < 128*96 + 32768){
    int j = t - 128*96 - 16384; int n = j/128, k = j%128;
    wt2[j] = f2bf(W2[k*128 + n]);
  } else if(t < 128*96 + 32768 + 16*160){
    int j = t - 128*96 - 32768; int n = j/160, k = j%160;
    wtr[j] = f2bf((n < 3 && k < 155) ? Wr[k*3 + n] : 0.f);
  }
}

// ---------------- per-ray view-dir positional embedding ------------------------
__global__ __launch_bounds__(256) void k_viewemb(const float* __restrict__ vd,
                                                 float* __restrict__ ve)
{
  int t = blockIdx.x*256 + threadIdx.x;
  if(t >= NRAYS*27) return;
  int ray = t/27, c = t%27;
  float v;
  if(c < 3) v = vd[ray*3 + c];
  else if(c < 15){
    int q = c - 3; int ci = q/4, p = q%4;
    v = sinf(vd[ray*3 + ci] * (float)(1 << p));
  } else {
    int q = c - 15; int ci = q/4, p = q%4;
    v = cosf(vd[ray*3 + ci] * (float)(1 << p));
  }
  ve[t] = v;
}

// ---------------- voxel repack: density f32 + 12 bf16 feats = 32 B/voxel -------
__global__ __launch_bounds__(256) void k_repack(const float* __restrict__ density,
    const float* __restrict__ k0, uint4* __restrict__ packed)
{
  int v = blockIdx.x*256 + threadIdx.x;
  if(v >= NVOX) return;
  float d = density[v];
  const float4* kp = (const float4*)(k0 + (size_t)v*12);
  float4 a = kp[0], b = kp[1], c = kp[2];
  uint4 o0, o1;
  o0.x = __float_as_uint(d);
  o0.y = packbf(a.x, a.y); o0.z = packbf(a.z, a.w); o0.w = packbf(b.x, b.y);
  o1.x = packbf(b.z, b.w); o1.y = packbf(c.x, c.y); o1.z = packbf(c.z, c.w);
  o1.w = 0;
  packed[(size_t)v*2]   = o0;
  packed[(size_t)v*2+1] = o1;
}

// ---------------- fused: gather+alpha + MLP + head -> per-sample rgb -----------
// 32x32x16 MFMA with A=weights, B=activations -> D[neuron][sample]
template<int KDIM, int SROW, int DROW>
static __device__ inline void layer32(const unsigned short* src, unsigned short* dst,
    const unsigned short* __restrict__ wt, const float* __restrict__ bias,
    int wave, int ln, int kh)
{
  constexpr int NS = KDIM/16;
  int tile_s = wave & 1, tile_n = wave >> 1;
  const unsigned short* wbase = wt + (tile_n*32 + ln)*KDIM + kh*8;
  const unsigned short* abase = src + (tile_s*32 + ln)*SROW + kh*8;
  f32x16 acc = {0.f,0.f,0.f,0.f,0.f,0.f,0.f,0.f,0.f,0.f,0.f,0.f,0.f,0.f,0.f,0.f};
  #pragma unroll
  for(int st = 0; st < NS; ++st){
    bf16x8 af = *(const bf16x8*)(wbase + st*16);
    bf16x8 bfr = *(const bf16x8*)(abase + st*16);
    acc = __builtin_amdgcn_mfma_f32_32x32x16_bf16(af, bfr, acc, 0, 0, 0);
  }
  int scol = tile_s*32 + ln;
  #pragma unroll
  for(int g = 0; g < 4; ++g){
    int n0 = tile_n*32 + g*8 + kh*4;
    float4 bv = *(const float4*)(bias + n0);
    unsigned int lo = packbf(fmaxf(acc[4*g+0] + bv.x, 0.f), fmaxf(acc[4*g+1] + bv.y, 0.f));
    unsigned int hi = packbf(fmaxf(acc[4*g+2] + bv.z, 0.f), fmaxf(acc[4*g+3] + bv.w, 0.f));
    unsigned long long o = (unsigned long long)lo | ((unsigned long long)hi << 32);
    *(unsigned long long*)(dst + scol*DROW + n0) = o;
  }
}

template<int PACKED>
__global__ __launch_bounds__(512) void k_mlp(const float* __restrict__ xyz,
    const uint4* __restrict__ packed, const float* __restrict__ density,
    const float* __restrict__ k0,
    const void* __restrict__ mask, const int* __restrict__ flag,
    const int* __restrict__ ray_id,
    const unsigned short* __restrict__ wt0, const unsigned short* __restrict__ wt1,
    const unsigned short* __restrict__ wt2, const unsigned short* __restrict__ wtr,
    const float* __restrict__ b0, const float* __restrict__ b1,
    const float* __restrict__ b2, const float* __restrict__ br,
    const float* __restrict__ ve,
    float* __restrict__ alpha_w, float4* __restrict__ rgb_out)
{
  __shared__ alignas(16) unsigned short hA[64*ROWA];
  __shared__ alignas(16) unsigned short hB[64*ROWB];
  __shared__ float red[64][4];

  int tid = threadIdx.x;
  int lane = tid & 63, wave = tid >> 6;

  // ---- phase 0a: distributed gather. 64 lanes = 8 samples x 8 corners --------
  {
    int s8 = lane >> 3, corner = lane & 7;
    int smp = wave*8 + s8;
    int i = blockIdx.x*64 + smp;
    float x = xyz[3*i+0], y = xyz[3*i+1], z = xyz[3*i+2];
    Tri t = tri_setup(x, y, z);
    int dx = corner & 1, dy = (corner >> 1) & 1, dz = corner >> 2;
    float w = (dx ? t.wx1 : t.wx0) * (dy ? t.wy1 : t.wy0) * (dz ? t.wz1 : t.wz0);
    size_t vox = (size_t)((t.ix+dx)*GYZ + (t.iy+dy)*GZD + (t.iz+dz));
    float pd;
    float pf[12];
    if(PACKED){
      const uint4* pv = packed + vox*2;
      uint4 q0 = pv[0], q1 = pv[1];
      pd = w * __uint_as_float(q0.x);
      pf[0] = w*flo(q0.y); pf[1] = w*fhi(q0.y);
      pf[2] = w*flo(q0.z); pf[3] = w*fhi(q0.z);
      pf[4] = w*flo(q0.w); pf[5] = w*fhi(q0.w);
      pf[6] = w*flo(q1.x); pf[7] = w*fhi(q1.x);
      pf[8] = w*flo(q1.y); pf[9] = w*fhi(q1.y);
      pf[10]= w*flo(q1.z); pf[11]= w*fhi(q1.z);
    } else {
      pd = w * density[vox];
      const float4* v = (const float4*)(k0 + vox*12);
      float4 a0 = v[0], a1 = v[1], a2 = v[2];
      pf[0] = w*a0.x; pf[1] = w*a0.y; pf[2] = w*a0.z; pf[3] = w*a0.w;
      pf[4] = w*a1.x; pf[5] = w*a1.y; pf[6] = w*a1.z; pf[7] = w*a1.w;
      pf[8] = w*a2.x; pf[9] = w*a2.y; pf[10]= w*a2.z; pf[11]= w*a2.w;
    }
    // butterfly reduce over the 8-corner group
    #pragma unroll
    for(int m2 = 1; m2 < 8; m2 <<= 1){
      pd += __shfl_xor(pd, m2);
      #pragma unroll
      for(int j = 0; j < 12; ++j) pf[j] += __shfl_xor(pf[j], m2);
    }
    if(corner == 0){
      // mask + alpha (free by-product of the density gather)
      int mx = (int)rintf(x*79.5f + 79.5f); mx = min(max(mx,0), GXD-1);
      int my = (int)rintf(y*79.5f + 79.5f); my = min(max(my,0), GYD-1);
      int mz = (int)rintf(z*63.5f + 63.5f); mz = min(max(mz,0), GZD-1);
      int midx = mx*GYZ + my*GZD + mz;
      bool mm = (*flag) ? (((const unsigned char*)mask)[midx] != 0)
                        : (((const int*)mask)[midx] != 0);
      float e = expf(pd + ACT_SHIFT);
      float alpha = 1.f - rsqrtf(1.f + e);   // (1+e)^(-0.5), INTERVAL=0.5
      if(!mm) alpha = 0.f;
      alpha_w[i] = alpha;
      // h0 cols 0..15: feat(12) | x y z | sin(x)
      unsigned int d[8];
      #pragma unroll
      for(int j = 0; j < 6; ++j) d[j] = packbf(pf[2*j], pf[2*j+1]);
      d[6] = packbf(x, y);
      d[7] = packbf(z, __sinf(x));
      uint4* p = (uint4*)(hA + smp*ROWA);
      p[0] = make_uint4(d[0],d[1],d[2],d[3]);
      p[1] = make_uint4(d[4],d[5],d[6],d[7]);
    }
  }

  // ---- phase 0b: posemb cols 16..95 (waves 1-5), ve cols (waves 6-7) ---------
  int i2 = blockIdx.x*64 + lane;
  if(wave >= 1 && wave < 6){
    float x = xyz[3*i2+0], y = xyz[3*i2+1], z = xyz[3*i2+2];
    float v[16];
    #pragma unroll
    for(int j = 0; j < 16; ++j){
      int c = wave*16 + j;
      float r;
      if(c >= 75) r = 0.f;
      else {
        int q = (c < 45) ? (c-15) : (c-45);
        int ci = q/10, p = q - ci*10;
        float xv = (ci == 0) ? x : ((ci == 1) ? y : z);
        float a = xv * (float)(1 << p);
        r = (c < 45) ? __sinf(a) : __cosf(a);
      }
      v[j] = r;
    }
    unsigned int d[8];
    #pragma unroll
    for(int j = 0; j < 8; ++j) d[j] = packbf(v[2*j], v[2*j+1]);
    uint4* p = (uint4*)(hA + lane*ROWA + wave*16);
    p[0] = make_uint4(d[0],d[1],d[2],d[3]);
    p[1] = make_uint4(d[4],d[5],d[6],d[7]);
  } else if(wave >= 6){
    int ray = ray_id[i2];
    int base = 128 + (wave-6)*16;
    unsigned int d[8];
    #pragma unroll
    for(int j = 0; j < 8; ++j){
      int c0i = base - 128 + 2*j;
      float a = (c0i     < 27) ? ve[ray*27 + c0i]     : 0.f;
      float b = (c0i + 1 < 27) ? ve[ray*27 + c0i + 1] : 0.f;
      d[j] = packbf(a, b);
    }
    uint4* p = (uint4*)(hB + lane*ROWB + base);
    p[0] = make_uint4(d[0],d[1],d[2],d[3]);
    p[1] = make_uint4(d[4],d[5],d[6],d[7]);
  }
  __syncthreads();

  int ln = lane & 31, kh = lane >> 5;
  layer32< 96, ROWA, ROWB>(hA, hB, wt0, b0, wave, ln, kh);  __syncthreads();
  layer32<128, ROWB, ROWA>(hB, hA, wt1, b1, wave, ln, kh);  __syncthreads();
  layer32<128, ROWA, ROWB>(hA, hB, wt2, b2, wave, ln, kh);  __syncthreads();

  // rgb head via 16x16x32 MFMA, K=160 (128 h + 27 ve + 5 pad), waves 0..3
  int col = lane & 15, q = lane >> 4;
  if(wave < 4){
    int mt = wave;
    f32x4 acc = {0.f, 0.f, 0.f, 0.f};
    const unsigned short* arow = hB + (mt*16 + col)*ROWB + q*8;
    const unsigned short* wrow = wtr + col*160 + q*8;
    #pragma unroll
    for(int ks = 0; ks < 5; ++ks){
      bf16x8 af = *(const bf16x8*)(arow + ks*32);
      bf16x8 bfr = *(const bf16x8*)(wrow + ks*32);
      acc = __builtin_amdgcn_mfma_f32_16x16x32_bf16(af, bfr, acc, 0, 0, 0);
    }
    if(col < 3){
      #pragma unroll
      for(int r = 0; r < 4; ++r){
        int sl = mt*16 + q*4 + r;
        float v = acc[r] + br[col];
        red[sl][col] = 1.f / (1.f + expf(-v));
      }
    }
  }
  __syncthreads();

  // coalesced per-sample rgb store (unweighted; composite happens in k_comp2)
  if(wave == 7){
    float4 o = make_float4(red[lane][0], red[lane][1], red[lane][2], 0.f);
    rgb_out[i2] = o;
  }
}

// ---------------- per-ray: alpha scan + weighted composite in one pass ---------
__global__ __launch_bounds__(256) void k_comp2(const int* __restrict__ ray_id,
    const float* __restrict__ alpha_w, const float4* __restrict__ rgb,
    float* __restrict__ out)
{
  int r = blockIdx.x*4 + (threadIdx.x >> 6);   // grid = NRAYS/4 blocks
  int lane = threadIdx.x & 63;
  int lo = 0, hi = M_SAMPLES;
  while(lo < hi){ int mid = (lo+hi) >> 1; if(ray_id[mid] < r) lo = mid+1; else hi = mid; }
  int s = lo;
  int lo2 = s, hi2 = M_SAMPLES;
  while(lo2 < hi2){ int mid = (lo2+hi2) >> 1; if(ray_id[mid] < r+1) lo2 = mid+1; else hi2 = mid; }
  int e = lo2;

  float carry = 1.f;
  float ar = 0.f, ag = 0.f, ab = 0.f;
  for(int base = s; base < e; base += 64){
    int idx = base + lane;
    float a = (idx < e) ? alpha_w[idx] : 0.f;
    float incl = 1.f - a;
    #pragma unroll
    for(int d2 = 1; d2 < 64; d2 <<= 1){
      float t = __shfl_up(incl, d2);
      if(lane >= d2) incl *= t;
    }
    float excl = __shfl_up(incl, 1);
    if(lane == 0) excl = 1.f;
    float w = carry * excl * a;
    if(idx < e){
      float4 c = rgb[idx];
      ar += w*c.x; ag += w*c.y; ab += w*c.z;
    }
    carry *= __shfl(incl, 63);
  }
  #pragma unroll
  for(int m2 = 1; m2 < 64; m2 <<= 1){
    ar += __shfl_xor(ar, m2);
    ag += __shfl_xor(ag, m2);
    ab += __shfl_xor(ab, m2);
  }
  if(lane == 0){
    out[3*r+0] = ar + carry;
    out[3*r+1] = ag + carry;
    out[3*r+2] = ab + carry;
  }
}

// ---------------- host ----------------------------------------------------------
extern "C" void kernel_launch(void* const* d_in, const int* in_sizes, int n_in,
                              void* d_out, int out_size, void* d_ws, size_t ws_size,
                              hipStream_t stream)
{
  const float* xyz      = (const float*)d_in[0];
  const int*   ray_id   = (const int*)  d_in[1];
  const float* viewdirs = (const float*)d_in[2];
  const void*  mask     =               d_in[3];
  const float* density  = (const float*)d_in[4];
  const float* k0       = (const float*)d_in[5];
  const float* W0 = (const float*)d_in[6];  const float* b0 = (const float*)d_in[7];
  const float* W1 = (const float*)d_in[8];  const float* b1 = (const float*)d_in[9];
  const float* W2 = (const float*)d_in[10]; const float* b2 = (const float*)d_in[11];
  const float* Wr = (const float*)d_in[12]; const float* br = (const float*)d_in[13];
  float* out = (float*)d_out;

  char* ws = (char*)d_ws;
  size_t off = 0;
  auto take = [&](size_t nbytes) -> void* {
    void* p = ws + off;
    off = (off + nbytes + 255) & ~(size_t)255;
    return p;
  };
  int*            flag    = (int*)           take(4);
  unsigned short* wt0     = (unsigned short*)take(128*96*2);
  unsigned short* wt1     = (unsigned short*)take(128*128*2);
  unsigned short* wt2     = (unsigned short*)take(128*128*2);
  unsigned short* wtr     = (unsigned short*)take(16*160*2);
  float*          ve      = (float*)         take((size_t)NRAYS*27*4);
  float*          alpha_w = (float*)         take((size_t)M_SAMPLES*4);
  float4*         rgb_ws  = (float4*)        take((size_t)M_SAMPLES*16);
  uint4*          packed  = (uint4*)         take((size_t)NVOX*32);
  bool use_packed = (ws_size >= off);

  k_detect <<<1,   64,  0, stream>>>((const unsigned int*)mask, flag);
  k_prep_w <<<186, 256, 0, stream>>>(W0, W1, W2, Wr, wt0, wt1, wt2, wtr);
  k_viewemb<<<864, 256, 0, stream>>>(viewdirs, ve);
  if(use_packed){
    k_repack<<<(NVOX+255)/256, 256, 0, stream>>>(density, k0, packed);
    k_mlp<1><<<M_SAMPLES/64, 512, 0, stream>>>(xyz, packed, density, k0, mask, flag,
                                               ray_id, wt0, wt1, wt2, wtr,
                                               b0, b1, b2, br, ve, alpha_w, rgb_ws);
  } else {
    k_mlp<0><<<M_SAMPLES/64, 512, 0, stream>>>(xyz, (const uint4*)k0, density, k0, mask, flag,
                                               ray_id, wt0, wt1, wt2, wtr,
                                               b0, b1, b2, br, ve, alpha_w, rgb_ws);
  }
  k_comp2  <<<NRAYS/4, 256, 0, stream>>>(ray_id, alpha_w, rgb_ws, out);
}

// Round 8
// 488.755 us; speedup vs baseline: 1.2474x; 1.0665x over previous
//
#include <hip/hip_runtime.h>
#include <hip/hip_bf16.h>

#define M_SAMPLES 524288
#define NRAYS 8192
#define GXD 160
#define GYD 160
#define GZD 128
#define GYZ (GYD*GZD)
#define NVOX (GXD*GYD*GZD)
#define ACT_SHIFT -13.81550955796f
#define ROWA 136      // hA leading dim (shorts)
#define ROWB 168      // hB leading dim (shorts)

typedef __bf16 bf16x8 __attribute__((ext_vector_type(8)));
typedef float f32x4 __attribute__((ext_vector_type(4)));
typedef float f32x16 __attribute__((ext_vector_type(16)));

static __device__ inline unsigned short f2bf(float f){
  __hip_bfloat16 h = __float2bfloat16(f);
  unsigned short u; __builtin_memcpy(&u, &h, 2); return u;
}

#if defined(__has_builtin)
#if __has_builtin(__builtin_amdgcn_cvt_pk_bf16_f32)
#define HAVE_PK_BF16 1
#endif
#endif

static __device__ inline unsigned int packbf(float a, float b){
#ifdef HAVE_PK_BF16
  typedef __bf16 bf16v2 __attribute__((ext_vector_type(2)));
  bf16v2 r = __builtin_amdgcn_cvt_pk_bf16_f32(a, b);
  unsigned int u; __builtin_memcpy(&u, &r, 4); return u;
#else
  return (unsigned int)f2bf(a) | ((unsigned int)f2bf(b) << 16);
#endif
}

struct Tri {
  int ix, iy, iz;
  float wx0, wx1, wy0, wy1, wz0, wz1;
};
static __device__ inline Tri tri_setup(float x, float y, float z){
  Tri t;
  float tx = (x+1.f)*0.5f*(float)(GXD-1); tx = fminf(fmaxf(tx,0.f),(float)(GXD-1));
  float ty = (y+1.f)*0.5f*(float)(GYD-1); ty = fminf(fmaxf(ty,0.f),(float)(GYD-1));
  float tz = (z+1.f)*0.5f*(float)(GZD-1); tz = fminf(fmaxf(tz,0.f),(float)(GZD-1));
  t.ix = min((int)tx, GXD-2); t.iy = min((int)ty, GYD-2); t.iz = min((int)tz, GZD-2);
  float fx = tx-t.ix, fy = ty-t.iy, fz = tz-t.iz;
  t.wx0 = 1.f-fx; t.wx1 = fx; t.wy0 = 1.f-fy; t.wy1 = fy; t.wz0 = 1.f-fz; t.wz1 = fz;
  return t;
}

// ---------------- mask dtype detection (numpy bool bytes vs int32) -------------
__global__ void k_detect(const unsigned int* __restrict__ mw, int* __restrict__ flag){
  unsigned int v = mw[threadIdx.x & 63];
  unsigned long long any = __ballot(v > 1u);
  if(threadIdx.x == 0) *flag = (any != 0ull) ? 1 : 0;   // 1 = byte format
}

// ---------------- weight transpose + bf16 convert ------------------------------
__global__ __launch_bounds__(256) void k_prep_w(const float* __restrict__ W0,
    const float* __restrict__ W1, const float* __restrict__ W2,
    const float* __restrict__ Wr,
    unsigned short* __restrict__ wt0, unsigned short* __restrict__ wt1,
    unsigned short* __restrict__ wt2, unsigned short* __restrict__ wtr)
{
  int t = blockIdx.x*256 + threadIdx.x;
  if(t < 128*96){
    int n = t/96, k = t%96;
    wt0[t] = f2bf((k < 75) ? W0[k*128 + n] : 0.f);
  } else if(t < 128*96 + 16384){
    int j = t - 128*96; int n = j/128, k = j%128;
    wt1[j] = f2bf(W1[k*128 + n]);
  } else if(t < 128*96 + 32768){
    int j = t - 128*96 - 16384; int n = j/128, k = j%128;
    wt2[j] = f2bf(W2[k*128 + n]);
  } else if(t < 128*96 + 32768 + 16*160){
    int j = t - 128*96 - 32768; int n = j/160, k = j%160;
    wtr[j] = f2bf((n < 3 && k < 155) ? Wr[k*3 + n] : 0.f);
  }
}

// ---------------- per-ray view-dir positional embedding ------------------------
__global__ __launch_bounds__(256) void k_viewemb(const float* __restrict__ vd,
                                                 float* __restrict__ ve)
{
  int t = blockIdx.x*256 + threadIdx.x;
  if(t >= NRAYS*27) return;
  int ray = t/27, c = t%27;
  float v;
  if(c < 3) v = vd[ray*3 + c];
  else if(c < 15){
    int q = c - 3; int ci = q/4, p = q%4;
    v = sinf(vd[ray*3 + ci] * (float)(1 << p));
  } else {
    int q = c - 15; int ci = q/4, p = q%4;
    v = cosf(vd[ray*3 + ci] * (float)(1 << p));
  }
  ve[t] = v;
}

// ---------------- fused: gather+alpha + MLP + head -> per-sample rgb -----------
// 32x32x16 MFMA with A=weights, B=activations -> D[neuron][sample]
template<int KDIM, int SROW, int DROW>
static __device__ inline void layer32(const unsigned short* src, unsigned short* dst,
    const unsigned short* __restrict__ wt, const float* __restrict__ bias,
    int wave, int ln, int kh)
{
  constexpr int NS = KDIM/16;
  int tile_s = wave & 1, tile_n = wave >> 1;
  const unsigned short* wbase = wt + (tile_n*32 + ln)*KDIM + kh*8;
  const unsigned short* abase = src + (tile_s*32 + ln)*SROW + kh*8;
  f32x16 acc = {0.f,0.f,0.f,0.f,0.f,0.f,0.f,0.f,0.f,0.f,0.f,0.f,0.f,0.f,0.f,0.f};
  #pragma unroll
  for(int st = 0; st < NS; ++st){
    bf16x8 af = *(const bf16x8*)(wbase + st*16);
    bf16x8 bfr = *(const bf16x8*)(abase + st*16);
    acc = __builtin_amdgcn_mfma_f32_32x32x16_bf16(af, bfr, acc, 0, 0, 0);
  }
  int scol = tile_s*32 + ln;
  #pragma unroll
  for(int g = 0; g < 4; ++g){
    int n0 = tile_n*32 + g*8 + kh*4;
    float4 bv = *(const float4*)(bias + n0);
    unsigned int lo = packbf(fmaxf(acc[4*g+0] + bv.x, 0.f), fmaxf(acc[4*g+1] + bv.y, 0.f));
    unsigned int hi = packbf(fmaxf(acc[4*g+2] + bv.z, 0.f), fmaxf(acc[4*g+3] + bv.w, 0.f));
    unsigned long long o = (unsigned long long)lo | ((unsigned long long)hi << 32);
    *(unsigned long long*)(dst + scol*DROW + n0) = o;
  }
}

__global__ __launch_bounds__(512) void k_mlp(const float* __restrict__ xyz,
    const float* __restrict__ density, const float* __restrict__ k0,
    const void* __restrict__ mask, const int* __restrict__ flag,
    const int* __restrict__ ray_id,
    const unsigned short* __restrict__ wt0, const unsigned short* __restrict__ wt1,
    const unsigned short* __restrict__ wt2, const unsigned short* __restrict__ wtr,
    const float* __restrict__ b0, const float* __restrict__ b1,
    const float* __restrict__ b2, const float* __restrict__ br,
    const float* __restrict__ ve,
    float* __restrict__ alpha_w, float4* __restrict__ rgb_out)
{
  __shared__ alignas(16) unsigned short hA[64*ROWA];
  __shared__ alignas(16) unsigned short hB[64*ROWB];
  __shared__ float red[64][4];

  int tid = threadIdx.x;
  int lane = tid & 63, wave = tid >> 6;

  if(wave < 4){
    // ---- gather: 64 lanes = 16 samples x 4 corners (dz merged in-thread) -----
    int smp = (wave << 4) | (lane >> 2);       // 0..63
    int corner = lane & 3;
    int i = blockIdx.x*64 + smp;
    float x = xyz[3*i+0], y = xyz[3*i+1], z = xyz[3*i+2];
    Tri t = tri_setup(x, y, z);
    int dx = corner & 1, dy = corner >> 1;
    float wxy = (dx ? t.wx1 : t.wx0) * (dy ? t.wy1 : t.wy0);
    float w0 = wxy*t.wz0, w1 = wxy*t.wz1;
    size_t vox = (size_t)((t.ix+dx)*GYZ + (t.iy+dy)*GZD + t.iz);
    float pd = w0*density[vox] + w1*density[vox+1];
    const float4* v = (const float4*)(k0 + vox*12);
    float4 a0 = v[0], a1 = v[1], a2 = v[2];
    float4 c0 = v[3], c1 = v[4], c2 = v[5];
    float pf[12];
    pf[0] = w0*a0.x + w1*c0.x;  pf[1] = w0*a0.y + w1*c0.y;
    pf[2] = w0*a0.z + w1*c0.z;  pf[3] = w0*a0.w + w1*c0.w;
    pf[4] = w0*a1.x + w1*c1.x;  pf[5] = w0*a1.y + w1*c1.y;
    pf[6] = w0*a1.z + w1*c1.z;  pf[7] = w0*a1.w + w1*c1.w;
    pf[8] = w0*a2.x + w1*c2.x;  pf[9] = w0*a2.y + w1*c2.y;
    pf[10]= w0*a2.z + w1*c2.z;  pf[11]= w0*a2.w + w1*c2.w;
    // 2-round butterfly over the 4-corner group (DPP quad_perm range)
    #pragma unroll
    for(int m2 = 1; m2 < 4; m2 <<= 1){
      pd += __shfl_xor(pd, m2);
      #pragma unroll
      for(int j = 0; j < 12; ++j) pf[j] += __shfl_xor(pf[j], m2);
    }
    if(corner == 0){
      int mx = (int)rintf(x*79.5f + 79.5f); mx = min(max(mx,0), GXD-1);
      int my = (int)rintf(y*79.5f + 79.5f); my = min(max(my,0), GYD-1);
      int mz = (int)rintf(z*63.5f + 63.5f); mz = min(max(mz,0), GZD-1);
      int midx = mx*GYZ + my*GZD + mz;
      bool mm = (*flag) ? (((const unsigned char*)mask)[midx] != 0)
                        : (((const int*)mask)[midx] != 0);
      float e = expf(pd + ACT_SHIFT);
      float alpha = 1.f - rsqrtf(1.f + e);   // (1+e)^(-0.5), INTERVAL=0.5
      if(!mm) alpha = 0.f;
      alpha_w[i] = alpha;
      unsigned int d[8];
      #pragma unroll
      for(int j = 0; j < 6; ++j) d[j] = packbf(pf[2*j], pf[2*j+1]);
      d[6] = packbf(x, y);
      d[7] = packbf(z, __sinf(x));           // col 15 = sin(x * 2^0)
      uint4* p = (uint4*)(hA + smp*ROWA);
      p[0] = make_uint4(d[0],d[1],d[2],d[3]);
      p[1] = make_uint4(d[4],d[5],d[6],d[7]);
    } else if(corner == 1){
      // cols 80..95 are all zero (h0 has 75 real channels)
      uint4* p = (uint4*)(hA + smp*ROWA + 80);
      p[0] = make_uint4(0,0,0,0);
      p[1] = make_uint4(0,0,0,0);
    } else {
      // ve staging: corner2 -> hB cols 128..143, corner3 -> 144..159
      int ray = ray_id[i];
      int cb = (corner - 2) * 16;
      unsigned int d[8];
      #pragma unroll
      for(int j = 0; j < 8; ++j){
        int c = cb + 2*j;
        float a = (c     < 27) ? ve[ray*27 + c]     : 0.f;
        float b = (c + 1 < 27) ? ve[ray*27 + c + 1] : 0.f;
        d[j] = packbf(a, b);
      }
      uint4* p = (uint4*)(hB + smp*ROWB + 128 + cb);
      p[0] = make_uint4(d[0],d[1],d[2],d[3]);
      p[1] = make_uint4(d[4],d[5],d[6],d[7]);
    }
  } else {
    // ---- posemb chunks 1..4 (cols 16..79), lane = sample ----------------------
    int chunk = wave - 3;                    // 1..4
    int i2 = blockIdx.x*64 + lane;
    float x = xyz[3*i2+0], y = xyz[3*i2+1], z = xyz[3*i2+2];
    float vv[16];
    #pragma unroll
    for(int j = 0; j < 16; ++j){
      int c = chunk*16 + j;
      float r;
      if(c >= 75) r = 0.f;
      else {
        int q = (c < 45) ? (c-15) : (c-45);
        int ci = q/10, p = q - ci*10;
        float xv = (ci == 0) ? x : ((ci == 1) ? y : z);
        float a = xv * (float)(1 << p);
        r = (c < 45) ? __sinf(a) : __cosf(a);
      }
      vv[j] = r;
    }
    unsigned int d[8];
    #pragma unroll
    for(int j = 0; j < 8; ++j) d[j] = packbf(vv[2*j], vv[2*j+1]);
    uint4* p = (uint4*)(hA + lane*ROWA + chunk*16);
    p[0] = make_uint4(d[0],d[1],d[2],d[3]);
    p[1] = make_uint4(d[4],d[5],d[6],d[7]);
  }
  __syncthreads();

  int ln = lane & 31, kh = lane >> 5;
  layer32< 96, ROWA, ROWB>(hA, hB, wt0, b0, wave, ln, kh);  __syncthreads();
  layer32<128, ROWB, ROWA>(hB, hA, wt1, b1, wave, ln, kh);  __syncthreads();
  layer32<128, ROWA, ROWB>(hA, hB, wt2, b2, wave, ln, kh);  __syncthreads();

  // rgb head via 16x16x32 MFMA, K=160 (128 h + 27 ve + 5 pad), waves 0..3
  int col = lane & 15, q = lane >> 4;
  if(wave < 4){
    int mt = wave;
    f32x4 acc = {0.f, 0.f, 0.f, 0.f};
    const unsigned short* arow = hB + (mt*16 + col)*ROWB + q*8;
    const unsigned short* wrow = wtr + col*160 + q*8;
    #pragma unroll
    for(int ks = 0; ks < 5; ++ks){
      bf16x8 af = *(const bf16x8*)(arow + ks*32);
      bf16x8 bfr = *(const bf16x8*)(wrow + ks*32);
      acc = __builtin_amdgcn_mfma_f32_16x16x32_bf16(af, bfr, acc, 0, 0, 0);
    }
    if(col < 3){
      #pragma unroll
      for(int r = 0; r < 4; ++r){
        int sl = mt*16 + q*4 + r;
        float v = acc[r] + br[col];
        red[sl][col] = 1.f / (1.f + expf(-v));
      }
    }
  }
  __syncthreads();

  // coalesced per-sample rgb store (unweighted; composite happens in k_comp2)
  if(wave == 7){
    int i2 = blockIdx.x*64 + lane;
    rgb_out[i2] = make_float4(red[lane][0], red[lane][1], red[lane][2], 0.f);
  }
}

// ---------------- per-ray: alpha scan + weighted composite in one pass ---------
__global__ __launch_bounds__(256) void k_comp2(const int* __restrict__ ray_id,
    const float* __restrict__ alpha_w, const float4* __restrict__ rgb,
    float* __restrict__ out)
{
  int r = blockIdx.x*4 + (threadIdx.x >> 6);   // grid = NRAYS/4 blocks
  int lane = threadIdx.x & 63;
  int lo = 0, hi = M_SAMPLES;
  while(lo < hi){ int mid = (lo+hi) >> 1; if(ray_id[mid] < r) lo = mid+1; else hi = mid; }
  int s = lo;
  int lo2 = s, hi2 = M_SAMPLES;
  while(lo2 < hi2){ int mid = (lo2+hi2) >> 1; if(ray_id[mid] < r+1) lo2 = mid+1; else hi2 = mid; }
  int e = lo2;

  float carry = 1.f;
  float ar = 0.f, ag = 0.f, ab = 0.f;
  for(int base = s; base < e; base += 64){
    int idx = base + lane;
    float a = (idx < e) ? alpha_w[idx] : 0.f;
    float incl = 1.f - a;
    #pragma unroll
    for(int d2 = 1; d2 < 64; d2 <<= 1){
      float t = __shfl_up(incl, d2);
      if(lane >= d2) incl *= t;
    }
    float excl = __shfl_up(incl, 1);
    if(lane == 0) excl = 1.f;
    float w = carry * excl * a;
    if(idx < e){
      float4 c = rgb[idx];
      ar += w*c.x; ag += w*c.y; ab += w*c.z;
    }
    carry *= __shfl(incl, 63);
  }
  #pragma unroll
  for(int m2 = 1; m2 < 64; m2 <<= 1){
    ar += __shfl_xor(ar, m2);
    ag += __shfl_xor(ag, m2);
    ab += __shfl_xor(ab, m2);
  }
  if(lane == 0){
    out[3*r+0] = ar + carry;
    out[3*r+1] = ag + carry;
    out[3*r+2] = ab + carry;
  }
}

// ---------------- host ----------------------------------------------------------
extern "C" void kernel_launch(void* const* d_in, const int* in_sizes, int n_in,
                              void* d_out, int out_size, void* d_ws, size_t ws_size,
                              hipStream_t stream)
{
  const float* xyz      = (const float*)d_in[0];
  const int*   ray_id   = (const int*)  d_in[1];
  const float* viewdirs = (const float*)d_in[2];
  const void*  mask     =               d_in[3];
  const float* density  = (const float*)d_in[4];
  const float* k0       = (const float*)d_in[5];
  const float* W0 = (const float*)d_in[6];  const float* b0 = (const float*)d_in[7];
  const float* W1 = (const float*)d_in[8];  const float* b1 = (const float*)d_in[9];
  const float* W2 = (const float*)d_in[10]; const float* b2 = (const float*)d_in[11];
  const float* Wr = (const float*)d_in[12]; const float* br = (const float*)d_in[13];
  float* out = (float*)d_out;

  char* ws = (char*)d_ws;
  size_t off = 0;
  auto take = [&](size_t nbytes) -> void* {
    void* p = ws + off;
    off = (off + nbytes + 255) & ~(size_t)255;
    return p;
  };
  int*            flag    = (int*)           take(4);
  unsigned short* wt0     = (unsigned short*)take(128*96*2);
  unsigned short* wt1     = (unsigned short*)take(128*128*2);
  unsigned short* wt2     = (unsigned short*)take(128*128*2);
  unsigned short* wtr     = (unsigned short*)take(16*160*2);
  float*          ve      = (float*)         take((size_t)NRAYS*27*4);
  float*          alpha_w = (float*)         take((size_t)M_SAMPLES*4);
  float4*         rgb_ws  = (float4*)        take((size_t)M_SAMPLES*16);

  k_detect <<<1,   64,  0, stream>>>((const unsigned int*)mask, flag);
  k_prep_w <<<186, 256, 0, stream>>>(W0, W1, W2, Wr, wt0, wt1, wt2, wtr);
  k_viewemb<<<864, 256, 0, stream>>>(viewdirs, ve);
  k_mlp    <<<M_SAMPLES/64, 512, 0, stream>>>(xyz, density, k0, mask, flag,
                                              ray_id, wt0, wt1, wt2, wtr,
                                              b0, b1, b2, br, ve, alpha_w, rgb_ws);
  k_comp2  <<<NRAYS/4, 256, 0, stream>>>(ray_id, alpha_w, rgb_ws, out);
}

// Round 9
// 486.892 us; speedup vs baseline: 1.2521x; 1.0038x over previous
//
#include <hip/hip_runtime.h>
#include <hip/hip_bf16.h>

#define M_SAMPLES 524288
#define NRAYS 8192
#define GXD 160
#define GYD 160
#define GZD 128
#define GYZ (GYD*GZD)
#define NVOX (GXD*GYD*GZD)
#define ACT_SHIFT -13.81550955796f
#define ROWA 136      // hA leading dim (shorts)
#define ROWB 168      // hB leading dim (shorts)

typedef __bf16 bf16x8 __attribute__((ext_vector_type(8)));
typedef float f32x4 __attribute__((ext_vector_type(4)));
typedef float f32x16 __attribute__((ext_vector_type(16)));
typedef float f32v2 __attribute__((ext_vector_type(2)));

static __device__ inline unsigned short f2bf(float f){
  __hip_bfloat16 h = __float2bfloat16(f);
  unsigned short u; __builtin_memcpy(&u, &h, 2); return u;
}
static __device__ inline float flo(unsigned int u){ return __uint_as_float(u << 16); }
static __device__ inline float fhi(unsigned int u){ return __uint_as_float(u & 0xffff0000u); }

#if defined(__has_builtin)
#if __has_builtin(__builtin_amdgcn_cvt_pk_bf16_f32)
#define HAVE_PK_BF16 1
#endif
#if __has_builtin(__builtin_amdgcn_cvt_pk_f32_fp8) && __has_builtin(__builtin_amdgcn_cvt_pk_fp8_f32)
#define HAVE_FP8 1
#endif
#endif

static __device__ inline unsigned int packbf(float a, float b){
#ifdef HAVE_PK_BF16
  typedef __bf16 bf16v2 __attribute__((ext_vector_type(2)));
  bf16v2 r = __builtin_amdgcn_cvt_pk_bf16_f32(a, b);
  unsigned int u; __builtin_memcpy(&u, &r, 4); return u;
#else
  return (unsigned int)f2bf(a) | ((unsigned int)f2bf(b) << 16);
#endif
}

struct Tri {
  int ix, iy, iz;
  float wx0, wx1, wy0, wy1, wz0, wz1;
};
static __device__ inline Tri tri_setup(float x, float y, float z){
  Tri t;
  float tx = (x+1.f)*0.5f*(float)(GXD-1); tx = fminf(fmaxf(tx,0.f),(float)(GXD-1));
  float ty = (y+1.f)*0.5f*(float)(GYD-1); ty = fminf(fmaxf(ty,0.f),(float)(GYD-1));
  float tz = (z+1.f)*0.5f*(float)(GZD-1); tz = fminf(fmaxf(tz,0.f),(float)(GZD-1));
  t.ix = min((int)tx, GXD-2); t.iy = min((int)ty, GYD-2); t.iz = min((int)tz, GZD-2);
  float fx = tx-t.ix, fy = ty-t.iy, fz = tz-t.iz;
  t.wx0 = 1.f-fx; t.wx1 = fx; t.wy0 = 1.f-fy; t.wy1 = fy; t.wz0 = 1.f-fz; t.wz1 = fz;
  return t;
}

// ---------------- merged prologue: detect | weight transpose | view posemb -----
__global__ __launch_bounds__(256) void k_prep(const unsigned int* __restrict__ mw,
    int* __restrict__ flag,
    const float* __restrict__ W0, const float* __restrict__ W1,
    const float* __restrict__ W2, const float* __restrict__ Wr,
    unsigned short* __restrict__ wt0, unsigned short* __restrict__ wt1,
    unsigned short* __restrict__ wt2, unsigned short* __restrict__ wtr,
    const float* __restrict__ vd, float* __restrict__ ve)
{
  int b = blockIdx.x;
  if(b == 0){
    unsigned int v = mw[threadIdx.x & 63];
    unsigned long long any = __ballot(v > 1u);
    if(threadIdx.x == 0) *flag = (any != 0ull) ? 1 : 0;   // 1 = byte mask
    return;
  }
  if(b < 187){
    int t = (b-1)*256 + threadIdx.x;
    if(t < 128*96){
      int n = t/96, k = t%96;
      wt0[t] = f2bf((k < 75) ? W0[k*128 + n] : 0.f);
    } else if(t < 128*96 + 16384){
      int j = t - 128*96; int n = j/128, k = j%128;
      wt1[j] = f2bf(W1[k*128 + n]);
    } else if(t < 128*96 + 32768){
      int j = t - 128*96 - 16384; int n = j/128, k = j%128;
      wt2[j] = f2bf(W2[k*128 + n]);
    } else if(t < 128*96 + 32768 + 16*160){
      int j = t - 128*96 - 32768; int n = j/160, k = j%160;
      wtr[j] = f2bf((n < 3 && k < 155) ? Wr[k*3 + n] : 0.f);
    }
    return;
  }
  int t = (b-187)*256 + threadIdx.x;
  if(t >= NRAYS*27) return;
  int ray = t/27, c = t%27;
  float v;
  if(c < 3) v = vd[ray*3 + c];
  else if(c < 15){
    int q = c - 3; int ci = q/4, p = q%4;
    v = sinf(vd[ray*3 + ci] * (float)(1 << p));
  } else {
    int q = c - 15; int ci = q/4, p = q%4;
    v = cosf(vd[ray*3 + ci] * (float)(1 << p));
  }
  ve[t] = v;
}

// ---------------- voxel repack ---------------------------------------------------
#ifdef HAVE_FP8
// 16 B/voxel: f32 density + 12 fp8-e4m3 features
__global__ __launch_bounds__(256) void k_repack(const float* __restrict__ density,
    const float* __restrict__ k0, uint4* __restrict__ packed)
{
  int v = blockIdx.x*256 + threadIdx.x;
  if(v >= NVOX) return;
  const float4* kp = (const float4*)(k0 + (size_t)v*12);
  float4 a = kp[0], b = kp[1], c = kp[2];
  uint4 o;
  o.x = __float_as_uint(density[v]);
  int w;
  w = __builtin_amdgcn_cvt_pk_fp8_f32(a.x, a.y, 0, false);
  w = __builtin_amdgcn_cvt_pk_fp8_f32(a.z, a.w, w, true);
  o.y = (unsigned int)w;
  w = __builtin_amdgcn_cvt_pk_fp8_f32(b.x, b.y, 0, false);
  w = __builtin_amdgcn_cvt_pk_fp8_f32(b.z, b.w, w, true);
  o.z = (unsigned int)w;
  w = __builtin_amdgcn_cvt_pk_fp8_f32(c.x, c.y, 0, false);
  w = __builtin_amdgcn_cvt_pk_fp8_f32(c.z, c.w, w, true);
  o.w = (unsigned int)w;
  packed[v] = o;
}
#else
// 32 B/voxel: f32 density + 12 bf16 features
__global__ __launch_bounds__(256) void k_repack(const float* __restrict__ density,
    const float* __restrict__ k0, uint4* __restrict__ packed)
{
  int v = blockIdx.x*256 + threadIdx.x;
  if(v >= NVOX) return;
  const float4* kp = (const float4*)(k0 + (size_t)v*12);
  float4 a = kp[0], b = kp[1], c = kp[2];
  uint4 o0, o1;
  o0.x = __float_as_uint(density[v]);
  o0.y = packbf(a.x, a.y); o0.z = packbf(a.z, a.w); o0.w = packbf(b.x, b.y);
  o1.x = packbf(b.z, b.w); o1.y = packbf(c.x, c.y); o1.z = packbf(c.z, c.w);
  o1.w = 0;
  packed[(size_t)v*2]   = o0;
  packed[(size_t)v*2+1] = o1;
}
#endif

// ---------------- fused: gather+alpha + MLP + head -> per-sample rgb -----------
template<int KDIM, int SROW, int DROW>
static __device__ inline void layer32(const unsigned short* src, unsigned short* dst,
    const unsigned short* __restrict__ wt, const float* __restrict__ bias,
    int wave, int ln, int kh)
{
  constexpr int NS = KDIM/16;
  int tile_s = wave & 1, tile_n = wave >> 1;
  const unsigned short* wbase = wt + (tile_n*32 + ln)*KDIM + kh*8;
  const unsigned short* abase = src + (tile_s*32 + ln)*SROW + kh*8;
  f32x16 acc = {0.f,0.f,0.f,0.f,0.f,0.f,0.f,0.f,0.f,0.f,0.f,0.f,0.f,0.f,0.f,0.f};
  #pragma unroll
  for(int st = 0; st < NS; ++st){
    bf16x8 af = *(const bf16x8*)(wbase + st*16);
    bf16x8 bfr = *(const bf16x8*)(abase + st*16);
    acc = __builtin_amdgcn_mfma_f32_32x32x16_bf16(af, bfr, acc, 0, 0, 0);
  }
  int scol = tile_s*32 + ln;
  #pragma unroll
  for(int g = 0; g < 4; ++g){
    int n0 = tile_n*32 + g*8 + kh*4;
    float4 bv = *(const float4*)(bias + n0);
    unsigned int lo = packbf(fmaxf(acc[4*g+0] + bv.x, 0.f), fmaxf(acc[4*g+1] + bv.y, 0.f));
    unsigned int hi = packbf(fmaxf(acc[4*g+2] + bv.z, 0.f), fmaxf(acc[4*g+3] + bv.w, 0.f));
    unsigned long long o = (unsigned long long)lo | ((unsigned long long)hi << 32);
    *(unsigned long long*)(dst + scol*DROW + n0) = o;
  }
}

template<int PACKED>
__global__ __launch_bounds__(512) void k_mlp(const float* __restrict__ xyz,
    const uint4* __restrict__ packed,
    const float* __restrict__ density, const float* __restrict__ k0,
    const void* __restrict__ mask, const int* __restrict__ flag,
    const int* __restrict__ ray_id,
    const unsigned short* __restrict__ wt0, const unsigned short* __restrict__ wt1,
    const unsigned short* __restrict__ wt2, const unsigned short* __restrict__ wtr,
    const float* __restrict__ b0, const float* __restrict__ b1,
    const float* __restrict__ b2, const float* __restrict__ br,
    const float* __restrict__ ve,
    float* __restrict__ alpha_w, float4* __restrict__ rgb_out)
{
  __shared__ alignas(16) unsigned short hA[64*ROWA];
  __shared__ alignas(16) unsigned short hB[64*ROWB];
  __shared__ float red[64][4];

  int tid = threadIdx.x;
  int lane = tid & 63, wave = tid >> 6;

  if(wave < 4){
    // ---- gather: 64 lanes = 16 samples x 4 corners (dz merged in-thread) -----
    int smp = (wave << 4) | (lane >> 2);       // 0..63
    int corner = lane & 3;
    int i = blockIdx.x*64 + smp;
    float x = xyz[3*i+0], y = xyz[3*i+1], z = xyz[3*i+2];
    Tri t = tri_setup(x, y, z);
    int dx = corner & 1, dy = corner >> 1;
    float wxy = (dx ? t.wx1 : t.wx0) * (dy ? t.wy1 : t.wy0);
    float w0 = wxy*t.wz0, w1 = wxy*t.wz1;
    size_t vox = (size_t)((t.ix+dx)*GYZ + (t.iy+dy)*GZD + t.iz);
    float pd;
    float pf[12];
#ifdef HAVE_FP8
    if(PACKED){
      uint4 q0 = packed[vox], q1 = packed[vox+1];
      pd = w0*__uint_as_float(q0.x) + w1*__uint_as_float(q1.x);
      f32v2 a, b;
      a = __builtin_amdgcn_cvt_pk_f32_fp8((int)q0.y, false);
      b = __builtin_amdgcn_cvt_pk_f32_fp8((int)q1.y, false);
      pf[0] = w0*a.x + w1*b.x;  pf[1] = w0*a.y + w1*b.y;
      a = __builtin_amdgcn_cvt_pk_f32_fp8((int)q0.y, true);
      b = __builtin_amdgcn_cvt_pk_f32_fp8((int)q1.y, true);
      pf[2] = w0*a.x + w1*b.x;  pf[3] = w0*a.y + w1*b.y;
      a = __builtin_amdgcn_cvt_pk_f32_fp8((int)q0.z, false);
      b = __builtin_amdgcn_cvt_pk_f32_fp8((int)q1.z, false);
      pf[4] = w0*a.x + w1*b.x;  pf[5] = w0*a.y + w1*b.y;
      a = __builtin_amdgcn_cvt_pk_f32_fp8((int)q0.z, true);
      b = __builtin_amdgcn_cvt_pk_f32_fp8((int)q1.z, true);
      pf[6] = w0*a.x + w1*b.x;  pf[7] = w0*a.y + w1*b.y;
      a = __builtin_amdgcn_cvt_pk_f32_fp8((int)q0.w, false);
      b = __builtin_amdgcn_cvt_pk_f32_fp8((int)q1.w, false);
      pf[8] = w0*a.x + w1*b.x;  pf[9] = w0*a.y + w1*b.y;
      a = __builtin_amdgcn_cvt_pk_f32_fp8((int)q0.w, true);
      b = __builtin_amdgcn_cvt_pk_f32_fp8((int)q1.w, true);
      pf[10]= w0*a.x + w1*b.x;  pf[11]= w0*a.y + w1*b.y;
    }
#else
    if(PACKED){
      const uint4* pv = packed + vox*2;
      uint4 q0 = pv[0], q1 = pv[1], q2 = pv[2], q3 = pv[3];
      pd = w0*__uint_as_float(q0.x) + w1*__uint_as_float(q2.x);
      pf[0]  = w0*flo(q0.y) + w1*flo(q2.y);  pf[1]  = w0*fhi(q0.y) + w1*fhi(q2.y);
      pf[2]  = w0*flo(q0.z) + w1*flo(q2.z);  pf[3]  = w0*fhi(q0.z) + w1*fhi(q2.z);
      pf[4]  = w0*flo(q0.w) + w1*flo(q2.w);  pf[5]  = w0*fhi(q0.w) + w1*fhi(q2.w);
      pf[6]  = w0*flo(q1.x) + w1*flo(q3.x);  pf[7]  = w0*fhi(q1.x) + w1*fhi(q3.x);
      pf[8]  = w0*flo(q1.y) + w1*flo(q3.y);  pf[9]  = w0*fhi(q1.y) + w1*fhi(q3.y);
      pf[10] = w0*flo(q1.z) + w1*flo(q3.z);  pf[11] = w0*fhi(q1.z) + w1*fhi(q3.z);
    }
#endif
    if(!PACKED){
      pd = w0*density[vox] + w1*density[vox+1];
      const float4* v = (const float4*)(k0 + vox*12);
      float4 a0 = v[0], a1 = v[1], a2 = v[2];
      float4 c0 = v[3], c1 = v[4], c2 = v[5];
      pf[0] = w0*a0.x + w1*c0.x;  pf[1] = w0*a0.y + w1*c0.y;
      pf[2] = w0*a0.z + w1*c0.z;  pf[3] = w0*a0.w + w1*c0.w;
      pf[4] = w0*a1.x + w1*c1.x;  pf[5] = w0*a1.y + w1*c1.y;
      pf[6] = w0*a1.z + w1*c1.z;  pf[7] = w0*a1.w + w1*c1.w;
      pf[8] = w0*a2.x + w1*c2.x;  pf[9] = w0*a2.y + w1*c2.y;
      pf[10]= w0*a2.z + w1*c2.z;  pf[11]= w0*a2.w + w1*c2.w;
    }
    // 2-round butterfly over the 4-corner group (DPP quad_perm range)
    #pragma unroll
    for(int m2 = 1; m2 < 4; m2 <<= 1){
      pd += __shfl_xor(pd, m2);
      #pragma unroll
      for(int j = 0; j < 12; ++j) pf[j] += __shfl_xor(pf[j], m2);
    }
    if(corner == 0){
      int mx = (int)rintf(x*79.5f + 79.5f); mx = min(max(mx,0), GXD-1);
      int my = (int)rintf(y*79.5f + 79.5f); my = min(max(my,0), GYD-1);
      int mz = (int)rintf(z*63.5f + 63.5f); mz = min(max(mz,0), GZD-1);
      int midx = mx*GYZ + my*GZD + mz;
      bool mm = (*flag) ? (((const unsigned char*)mask)[midx] != 0)
                        : (((const int*)mask)[midx] != 0);
      float e = expf(pd + ACT_SHIFT);
      float alpha = 1.f - rsqrtf(1.f + e);   // (1+e)^(-0.5), INTERVAL=0.5
      if(!mm) alpha = 0.f;
      alpha_w[i] = alpha;
      unsigned int d[8];
      #pragma unroll
      for(int j = 0; j < 6; ++j) d[j] = packbf(pf[2*j], pf[2*j+1]);
      d[6] = packbf(x, y);
      d[7] = packbf(z, __sinf(x));           // col 15 = sin(x * 2^0)
      uint4* p = (uint4*)(hA + smp*ROWA);
      p[0] = make_uint4(d[0],d[1],d[2],d[3]);
      p[1] = make_uint4(d[4],d[5],d[6],d[7]);
    } else if(corner == 1){
      uint4* p = (uint4*)(hA + smp*ROWA + 80);   // cols 80..95 zero
      p[0] = make_uint4(0,0,0,0);
      p[1] = make_uint4(0,0,0,0);
    } else {
      int ray = ray_id[i];
      int cb = (corner - 2) * 16;
      unsigned int d[8];
      #pragma unroll
      for(int j = 0; j < 8; ++j){
        int c = cb + 2*j;
        float a = (c     < 27) ? ve[ray*27 + c]     : 0.f;
        float b = (c + 1 < 27) ? ve[ray*27 + c + 1] : 0.f;
        d[j] = packbf(a, b);
      }
      uint4* p = (uint4*)(hB + smp*ROWB + 128 + cb);
      p[0] = make_uint4(d[0],d[1],d[2],d[3]);
      p[1] = make_uint4(d[4],d[5],d[6],d[7]);
    }
  } else {
    // ---- posemb chunks 1..4 (cols 16..79), lane = sample ----------------------
    int chunk = wave - 3;                    // 1..4
    int i2 = blockIdx.x*64 + lane;
    float x = xyz[3*i2+0], y = xyz[3*i2+1], z = xyz[3*i2+2];
    float vv[16];
    #pragma unroll
    for(int j = 0; j < 16; ++j){
      int c = chunk*16 + j;
      float r;
      if(c >= 75) r = 0.f;
      else {
        int q = (c < 45) ? (c-15) : (c-45);
        int ci = q/10, p = q - ci*10;
        float xv = (ci == 0) ? x : ((ci == 1) ? y : z);
        float a = xv * (float)(1 << p);
        r = (c < 45) ? __sinf(a) : __cosf(a);
      }
      vv[j] = r;
    }
    unsigned int d[8];
    #pragma unroll
    for(int j = 0; j < 8; ++j) d[j] = packbf(vv[2*j], vv[2*j+1]);
    uint4* p = (uint4*)(hA + lane*ROWA + chunk*16);
    p[0] = make_uint4(d[0],d[1],d[2],d[3]);
    p[1] = make_uint4(d[4],d[5],d[6],d[7]);
  }
  __syncthreads();

  int ln = lane & 31, kh = lane >> 5;
  layer32< 96, ROWA, ROWB>(hA, hB, wt0, b0, wave, ln, kh);  __syncthreads();
  layer32<128, ROWB, ROWA>(hB, hA, wt1, b1, wave, ln, kh);  __syncthreads();
  layer32<128, ROWA, ROWB>(hA, hB, wt2, b2, wave, ln, kh);  __syncthreads();

  // rgb head via 16x16x32 MFMA, K=160 (128 h + 27 ve + 5 pad), waves 0..3
  int col = lane & 15, q = lane >> 4;
  if(wave < 4){
    int mt = wave;
    f32x4 acc = {0.f, 0.f, 0.f, 0.f};
    const unsigned short* arow = hB + (mt*16 + col)*ROWB + q*8;
    const unsigned short* wrow = wtr + col*160 + q*8;
    #pragma unroll
    for(int ks = 0; ks < 5; ++ks){
      bf16x8 af = *(const bf16x8*)(arow + ks*32);
      bf16x8 bfr = *(const bf16x8*)(wrow + ks*32);
      acc = __builtin_amdgcn_mfma_f32_16x16x32_bf16(af, bfr, acc, 0, 0, 0);
    }
    if(col < 3){
      #pragma unroll
      for(int r = 0; r < 4; ++r){
        int sl = mt*16 + q*4 + r;
        float v = acc[r] + br[col];
        red[sl][col] = 1.f / (1.f + expf(-v));
      }
    }
  }
  __syncthreads();

  if(wave == 7){
    int i2 = blockIdx.x*64 + lane;
    rgb_out[i2] = make_float4(red[lane][0], red[lane][1], red[lane][2], 0.f);
  }
}

// ---------------- per-ray: alpha scan + weighted composite in one pass ---------
__global__ __launch_bounds__(256) void k_comp2(const int* __restrict__ ray_id,
    const float* __restrict__ alpha_w, const float4* __restrict__ rgb,
    float* __restrict__ out)
{
  int r = blockIdx.x*4 + (threadIdx.x >> 6);   // grid = NRAYS/4 blocks
  int lane = threadIdx.x & 63;
  int lo = 0, hi = M_SAMPLES;
  while(lo < hi){ int mid = (lo+hi) >> 1; if(ray_id[mid] < r) lo = mid+1; else hi = mid; }
  int s = lo;
  int lo2 = s, hi2 = M_SAMPLES;
  while(lo2 < hi2){ int mid = (lo2+hi2) >> 1; if(ray_id[mid] < r+1) lo2 = mid+1; else hi2 = mid; }
  int e = lo2;

  float carry = 1.f;
  float ar = 0.f, ag = 0.f, ab = 0.f;
  for(int base = s; base < e; base += 64){
    int idx = base + lane;
    float a = (idx < e) ? alpha_w[idx] : 0.f;
    float incl = 1.f - a;
    #pragma unroll
    for(int d2 = 1; d2 < 64; d2 <<= 1){
      float t = __shfl_up(incl, d2);
      if(lane >= d2) incl *= t;
    }
    float excl = __shfl_up(incl, 1);
    if(lane == 0) excl = 1.f;
    float w = carry * excl * a;
    if(idx < e){
      float4 c = rgb[idx];
      ar += w*c.x; ag += w*c.y; ab += w*c.z;
    }
    carry *= __shfl(incl, 63);
  }
  #pragma unroll
  for(int m2 = 1; m2 < 64; m2 <<= 1){
    ar += __shfl_xor(ar, m2);
    ag += __shfl_xor(ag, m2);
    ab += __shfl_xor(ab, m2);
  }
  if(lane == 0){
    out[3*r+0] = ar + carry;
    out[3*r+1] = ag + carry;
    out[3*r+2] = ab + carry;
  }
}

// ---------------- host ----------------------------------------------------------
extern "C" void kernel_launch(void* const* d_in, const int* in_sizes, int n_in,
                              void* d_out, int out_size, void* d_ws, size_t ws_size,
                              hipStream_t stream)
{
  const float* xyz      = (const float*)d_in[0];
  const int*   ray_id   = (const int*)  d_in[1];
  const float* viewdirs = (const float*)d_in[2];
  const void*  mask     =               d_in[3];
  const float* density  = (const float*)d_in[4];
  const float* k0       = (const float*)d_in[5];
  const float* W0 = (const float*)d_in[6];  const float* b0 = (const float*)d_in[7];
  const float* W1 = (const float*)d_in[8];  const float* b1 = (const float*)d_in[9];
  const float* W2 = (const float*)d_in[10]; const float* b2 = (const float*)d_in[11];
  const float* Wr = (const float*)d_in[12]; const float* br = (const float*)d_in[13];
  float* out = (float*)d_out;

  char* ws = (char*)d_ws;
  size_t off = 0;
  auto take = [&](size_t nbytes) -> void* {
    void* p = ws + off;
    off = (off + nbytes + 255) & ~(size_t)255;
    return p;
  };
  int*            flag    = (int*)           take(4);
  unsigned short* wt0     = (unsigned short*)take(128*96*2);
  unsigned short* wt1     = (unsigned short*)take(128*128*2);
  unsigned short* wt2     = (unsigned short*)take(128*128*2);
  unsigned short* wtr     = (unsigned short*)take(16*160*2);
  float*          ve      = (float*)         take((size_t)NRAYS*27*4);
  float*          alpha_w = (float*)         take((size_t)M_SAMPLES*4);
  float4*         rgb_ws  = (float4*)        take((size_t)M_SAMPLES*16);
#ifdef HAVE_FP8
  uint4*          packed  = (uint4*)         take((size_t)NVOX*16);
#else
  uint4*          packed  = (uint4*)         take((size_t)NVOX*32);
#endif
  bool use_packed = (ws_size >= off);

  k_prep<<<1051, 256, 0, stream>>>((const unsigned int*)mask, flag,
                                   W0, W1, W2, Wr, wt0, wt1, wt2, wtr, viewdirs, ve);
  if(use_packed){
    k_repack<<<(NVOX+255)/256, 256, 0, stream>>>(density, k0, packed);
    k_mlp<1><<<M_SAMPLES/64, 512, 0, stream>>>(xyz, packed, density, k0, mask, flag,
                                               ray_id, wt0, wt1, wt2, wtr,
                                               b0, b1, b2, br, ve, alpha_w, rgb_ws);
  } else {
    k_mlp<0><<<M_SAMPLES/64, 512, 0, stream>>>(xyz, packed, density, k0, mask, flag,
                                               ray_id, wt0, wt1, wt2, wtr,
                                               b0, b1, b2, br, ve, alpha_w, rgb_ws);
  }
  k_comp2<<<NRAYS/4, 256, 0, stream>>>(ray_id, alpha_w, rgb_ws, out);
}

// Round 10
// 434.902 us; speedup vs baseline: 1.4018x; 1.1195x over previous
//
#include <hip/hip_runtime.h>
#include <hip/hip_bf16.h>

#define M_SAMPLES 524288
#define NRAYS 8192
#define GXD 160
#define GYD 160
#define GZD 128
#define GYZ (GYD*GZD)
#define NVOX (GXD*GYD*GZD)
#define ACT_SHIFT -13.81550955796f
#define ROWA 136      // hA leading dim (shorts)
#define ROWB 168      // hB leading dim (shorts)
#define SAMP 128      // samples per k_mlp block

typedef __bf16 bf16x8 __attribute__((ext_vector_type(8)));
typedef float f32x4 __attribute__((ext_vector_type(4)));
typedef float f32x16 __attribute__((ext_vector_type(16)));
typedef float f32v2 __attribute__((ext_vector_type(2)));

static __device__ inline unsigned short f2bf(float f){
  __hip_bfloat16 h = __float2bfloat16(f);
  unsigned short u; __builtin_memcpy(&u, &h, 2); return u;
}
static __device__ inline float flo(unsigned int u){ return __uint_as_float(u << 16); }
static __device__ inline float fhi(unsigned int u){ return __uint_as_float(u & 0xffff0000u); }

#if defined(__has_builtin)
#if __has_builtin(__builtin_amdgcn_cvt_pk_bf16_f32)
#define HAVE_PK_BF16 1
#endif
#if __has_builtin(__builtin_amdgcn_cvt_pk_f32_fp8) && __has_builtin(__builtin_amdgcn_cvt_pk_fp8_f32)
#define HAVE_FP8 1
#endif
#endif

static __device__ inline unsigned int packbf(float a, float b){
#ifdef HAVE_PK_BF16
  typedef __bf16 bf16v2 __attribute__((ext_vector_type(2)));
  bf16v2 r = __builtin_amdgcn_cvt_pk_bf16_f32(a, b);
  unsigned int u; __builtin_memcpy(&u, &r, 4); return u;
#else
  return (unsigned int)f2bf(a) | ((unsigned int)f2bf(b) << 16);
#endif
}

struct Tri {
  int ix, iy, iz;
  float wx0, wx1, wy0, wy1, wz0, wz1;
};
static __device__ inline Tri tri_setup(float x, float y, float z){
  Tri t;
  float tx = (x+1.f)*0.5f*(float)(GXD-1); tx = fminf(fmaxf(tx,0.f),(float)(GXD-1));
  float ty = (y+1.f)*0.5f*(float)(GYD-1); ty = fminf(fmaxf(ty,0.f),(float)(GYD-1));
  float tz = (z+1.f)*0.5f*(float)(GZD-1); tz = fminf(fmaxf(tz,0.f),(float)(GZD-1));
  t.ix = min((int)tx, GXD-2); t.iy = min((int)ty, GYD-2); t.iz = min((int)tz, GZD-2);
  float fx = tx-t.ix, fy = ty-t.iy, fz = tz-t.iz;
  t.wx0 = 1.f-fx; t.wx1 = fx; t.wy0 = 1.f-fy; t.wy1 = fy; t.wz0 = 1.f-fz; t.wz1 = fz;
  return t;
}

// ---------------- merged prologue: repack | detect | weights | view posemb -----
#define NB_REPACK (NVOX/256)              // 12800
#define NB_W      186
#define NB_VE     864
__global__ __launch_bounds__(256) void k_prep(
    const float* __restrict__ density, const float* __restrict__ k0,
    uint4* __restrict__ packed,
    const unsigned int* __restrict__ mw, int* __restrict__ flag,
    const float* __restrict__ W0, const float* __restrict__ W1,
    const float* __restrict__ W2, const float* __restrict__ Wr,
    unsigned short* __restrict__ wt0, unsigned short* __restrict__ wt1,
    unsigned short* __restrict__ wt2, unsigned short* __restrict__ wtr,
    const float* __restrict__ vd, float* __restrict__ ve)
{
  int b = blockIdx.x;
  if(b < NB_REPACK){
    int v = b*256 + threadIdx.x;
    const float4* kp = (const float4*)(k0 + (size_t)v*12);
    float4 a = kp[0], bb = kp[1], c = kp[2];
#ifdef HAVE_FP8
    uint4 o;
    o.x = __float_as_uint(density[v]);
    int w;
    w = __builtin_amdgcn_cvt_pk_fp8_f32(a.x, a.y, 0, false);
    w = __builtin_amdgcn_cvt_pk_fp8_f32(a.z, a.w, w, true);
    o.y = (unsigned int)w;
    w = __builtin_amdgcn_cvt_pk_fp8_f32(bb.x, bb.y, 0, false);
    w = __builtin_amdgcn_cvt_pk_fp8_f32(bb.z, bb.w, w, true);
    o.z = (unsigned int)w;
    w = __builtin_amdgcn_cvt_pk_fp8_f32(c.x, c.y, 0, false);
    w = __builtin_amdgcn_cvt_pk_fp8_f32(c.z, c.w, w, true);
    o.w = (unsigned int)w;
    packed[v] = o;
#else
    uint4 o0, o1;
    o0.x = __float_as_uint(density[v]);
    o0.y = packbf(a.x, a.y); o0.z = packbf(a.z, a.w); o0.w = packbf(bb.x, bb.y);
    o1.x = packbf(bb.z, bb.w); o1.y = packbf(c.x, c.y); o1.z = packbf(c.z, c.w);
    o1.w = 0;
    packed[(size_t)v*2]   = o0;
    packed[(size_t)v*2+1] = o1;
#endif
    return;
  }
  if(b == NB_REPACK){
    unsigned int v = mw[threadIdx.x & 63];
    unsigned long long any = __ballot(v > 1u);
    if(threadIdx.x == 0) *flag = (any != 0ull) ? 1 : 0;   // 1 = byte mask
    return;
  }
  if(b < NB_REPACK + 1 + NB_W){
    int t = (b - NB_REPACK - 1)*256 + threadIdx.x;
    if(t < 128*96){
      int n = t/96, k = t%96;
      wt0[t] = f2bf((k < 75) ? W0[k*128 + n] : 0.f);
    } else if(t < 128*96 + 16384){
      int j = t - 128*96; int n = j/128, k = j%128;
      wt1[j] = f2bf(W1[k*128 + n]);
    } else if(t < 128*96 + 32768){
      int j = t - 128*96 - 16384; int n = j/128, k = j%128;
      wt2[j] = f2bf(W2[k*128 + n]);
    } else if(t < 128*96 + 32768 + 16*160){
      int j = t - 128*96 - 32768; int n = j/160, k = j%160;
      wtr[j] = f2bf((n < 3 && k < 155) ? Wr[k*3 + n] : 0.f);
    }
    return;
  }
  int t = (b - NB_REPACK - 1 - NB_W)*256 + threadIdx.x;
  if(t >= NRAYS*27) return;
  int ray = t/27, c = t%27;
  float v;
  if(c < 3) v = vd[ray*3 + c];
  else if(c < 15){
    int q = c - 3; int ci = q/4, p = q%4;
    v = sinf(vd[ray*3 + ci] * (float)(1 << p));
  } else {
    int q = c - 15; int ci = q/4, p = q%4;
    v = cosf(vd[ray*3 + ci] * (float)(1 << p));
  }
  ve[t] = v;
}

// ---------------- fused: gather+alpha + MLP + head -> per-sample rgba ----------
// 32x32x16 MFMA, A=weights B=activations -> D[neuron][sample].
// Each wave: one n-tile, two m-tiles (interleaved chains, shared weight frag).
template<int KDIM, int SROW, int DROW>
static __device__ inline void layer32(const unsigned short* src, unsigned short* dst,
    const unsigned short* __restrict__ wt, const float* __restrict__ bias,
    int wave, int ln, int kh)
{
  constexpr int NS = KDIM/16;
  int tile_n = wave >> 1;
  int m0 = (wave & 1) * 2;
  const unsigned short* wbase = wt + (tile_n*32 + ln)*KDIM + kh*8;
  const unsigned short* abase0 = src + ((m0  )*32 + ln)*SROW + kh*8;
  const unsigned short* abase1 = src + ((m0+1)*32 + ln)*SROW + kh*8;
  f32x16 acc0 = {0.f,0.f,0.f,0.f,0.f,0.f,0.f,0.f,0.f,0.f,0.f,0.f,0.f,0.f,0.f,0.f};
  f32x16 acc1 = acc0;
  #pragma unroll
  for(int st = 0; st < NS; ++st){
    bf16x8 wf = *(const bf16x8*)(wbase + st*16);
    bf16x8 a0 = *(const bf16x8*)(abase0 + st*16);
    bf16x8 a1 = *(const bf16x8*)(abase1 + st*16);
    acc0 = __builtin_amdgcn_mfma_f32_32x32x16_bf16(wf, a0, acc0, 0, 0, 0);
    acc1 = __builtin_amdgcn_mfma_f32_32x32x16_bf16(wf, a1, acc1, 0, 0, 0);
  }
  #pragma unroll
  for(int rep = 0; rep < 2; ++rep){
    const f32x16& acc = rep ? acc1 : acc0;
    int scol = (m0 + rep)*32 + ln;
    #pragma unroll
    for(int g = 0; g < 4; ++g){
      int n0 = tile_n*32 + g*8 + kh*4;
      float4 bv = *(const float4*)(bias + n0);
      unsigned int lo = packbf(fmaxf(acc[4*g+0] + bv.x, 0.f), fmaxf(acc[4*g+1] + bv.y, 0.f));
      unsigned int hi = packbf(fmaxf(acc[4*g+2] + bv.z, 0.f), fmaxf(acc[4*g+3] + bv.w, 0.f));
      unsigned long long o = (unsigned long long)lo | ((unsigned long long)hi << 32);
      *(unsigned long long*)(dst + scol*DROW + n0) = o;
    }
  }
}

template<int PACKED>
__global__ __launch_bounds__(512) void k_mlp(const float* __restrict__ xyz,
    const uint4* __restrict__ packed,
    const float* __restrict__ density, const float* __restrict__ k0,
    const void* __restrict__ mask, const int* __restrict__ flag,
    const int* __restrict__ ray_id,
    const unsigned short* __restrict__ wt0, const unsigned short* __restrict__ wt1,
    const unsigned short* __restrict__ wt2, const unsigned short* __restrict__ wtr,
    const float* __restrict__ b0, const float* __restrict__ b1,
    const float* __restrict__ b2, const float* __restrict__ br,
    const float* __restrict__ ve, float4* __restrict__ rgba_out)
{
  __shared__ alignas(16) unsigned short hA[SAMP*ROWA];
  __shared__ alignas(16) unsigned short hB[SAMP*ROWB];
  __shared__ float red[SAMP][4];

  int tid = threadIdx.x;
  int lane = tid & 63, wave = tid >> 6;
  int blk = blockIdx.x*SAMP;

  // ---- phase 0a: gather. 512 lanes = 128 samples x 4 corners (dz in-thread) --
  {
    int smp = tid >> 2, corner = tid & 3;
    int i = blk + smp;
    float x = xyz[3*i+0], y = xyz[3*i+1], z = xyz[3*i+2];
    Tri t = tri_setup(x, y, z);
    int dx = corner & 1, dy = corner >> 1;
    float wxy = (dx ? t.wx1 : t.wx0) * (dy ? t.wy1 : t.wy0);
    float w0 = wxy*t.wz0, w1 = wxy*t.wz1;
    size_t vox = (size_t)((t.ix+dx)*GYZ + (t.iy+dy)*GZD + t.iz);
    float pd;
    float pf[12];
#ifdef HAVE_FP8
    if(PACKED){
      uint4 q0 = packed[vox], q1 = packed[vox+1];
      pd = w0*__uint_as_float(q0.x) + w1*__uint_as_float(q1.x);
      f32v2 a, b;
      a = __builtin_amdgcn_cvt_pk_f32_fp8((int)q0.y, false);
      b = __builtin_amdgcn_cvt_pk_f32_fp8((int)q1.y, false);
      pf[0] = w0*a.x + w1*b.x;  pf[1] = w0*a.y + w1*b.y;
      a = __builtin_amdgcn_cvt_pk_f32_fp8((int)q0.y, true);
      b = __builtin_amdgcn_cvt_pk_f32_fp8((int)q1.y, true);
      pf[2] = w0*a.x + w1*b.x;  pf[3] = w0*a.y + w1*b.y;
      a = __builtin_amdgcn_cvt_pk_f32_fp8((int)q0.z, false);
      b = __builtin_amdgcn_cvt_pk_f32_fp8((int)q1.z, false);
      pf[4] = w0*a.x + w1*b.x;  pf[5] = w0*a.y + w1*b.y;
      a = __builtin_amdgcn_cvt_pk_f32_fp8((int)q0.z, true);
      b = __builtin_amdgcn_cvt_pk_f32_fp8((int)q1.z, true);
      pf[6] = w0*a.x + w1*b.x;  pf[7] = w0*a.y + w1*b.y;
      a = __builtin_amdgcn_cvt_pk_f32_fp8((int)q0.w, false);
      b = __builtin_amdgcn_cvt_pk_f32_fp8((int)q1.w, false);
      pf[8] = w0*a.x + w1*b.x;  pf[9] = w0*a.y + w1*b.y;
      a = __builtin_amdgcn_cvt_pk_f32_fp8((int)q0.w, true);
      b = __builtin_amdgcn_cvt_pk_f32_fp8((int)q1.w, true);
      pf[10]= w0*a.x + w1*b.x;  pf[11]= w0*a.y + w1*b.y;
    }
#else
    if(PACKED){
      const uint4* pv = packed + vox*2;
      uint4 q0 = pv[0], q1 = pv[1], q2 = pv[2], q3 = pv[3];
      pd = w0*__uint_as_float(q0.x) + w1*__uint_as_float(q2.x);
      pf[0]  = w0*flo(q0.y) + w1*flo(q2.y);  pf[1]  = w0*fhi(q0.y) + w1*fhi(q2.y);
      pf[2]  = w0*flo(q0.z) + w1*flo(q2.z);  pf[3]  = w0*fhi(q0.z) + w1*fhi(q2.z);
      pf[4]  = w0*flo(q0.w) + w1*flo(q2.w);  pf[5]  = w0*fhi(q0.w) + w1*fhi(q2.w);
      pf[6]  = w0*flo(q1.x) + w1*flo(q3.x);  pf[7]  = w0*fhi(q1.x) + w1*fhi(q3.x);
      pf[8]  = w0*flo(q1.y) + w1*flo(q3.y);  pf[9]  = w0*fhi(q1.y) + w1*fhi(q3.y);
      pf[10] = w0*flo(q1.z) + w1*flo(q3.z);  pf[11] = w0*fhi(q1.z) + w1*fhi(q3.z);
    }
#endif
    if(!PACKED){
      pd = w0*density[vox] + w1*density[vox+1];
      const float4* v = (const float4*)(k0 + vox*12);
      float4 a0 = v[0], a1 = v[1], a2 = v[2];
      float4 c0 = v[3], c1 = v[4], c2 = v[5];
      pf[0] = w0*a0.x + w1*c0.x;  pf[1] = w0*a0.y + w1*c0.y;
      pf[2] = w0*a0.z + w1*c0.z;  pf[3] = w0*a0.w + w1*c0.w;
      pf[4] = w0*a1.x + w1*c1.x;  pf[5] = w0*a1.y + w1*c1.y;
      pf[6] = w0*a1.z + w1*c1.z;  pf[7] = w0*a1.w + w1*c1.w;
      pf[8] = w0*a2.x + w1*c2.x;  pf[9] = w0*a2.y + w1*c2.y;
      pf[10]= w0*a2.z + w1*c2.z;  pf[11]= w0*a2.w + w1*c2.w;
    }
    #pragma unroll
    for(int m2 = 1; m2 < 4; m2 <<= 1){
      pd += __shfl_xor(pd, m2);
      #pragma unroll
      for(int j = 0; j < 12; ++j) pf[j] += __shfl_xor(pf[j], m2);
    }
    if(corner == 0){
      int mx = (int)rintf(x*79.5f + 79.5f); mx = min(max(mx,0), GXD-1);
      int my = (int)rintf(y*79.5f + 79.5f); my = min(max(my,0), GYD-1);
      int mz = (int)rintf(z*63.5f + 63.5f); mz = min(max(mz,0), GZD-1);
      int midx = mx*GYZ + my*GZD + mz;
      bool mm = (*flag) ? (((const unsigned char*)mask)[midx] != 0)
                        : (((const int*)mask)[midx] != 0);
      float e = expf(pd + ACT_SHIFT);
      float alpha = 1.f - rsqrtf(1.f + e);   // (1+e)^(-0.5), INTERVAL=0.5
      if(!mm) alpha = 0.f;
      red[smp][3] = alpha;                   // rides out in rgba.w
      unsigned int d[8];
      #pragma unroll
      for(int j = 0; j < 6; ++j) d[j] = packbf(pf[2*j], pf[2*j+1]);
      d[6] = packbf(x, y);
      d[7] = packbf(z, __sinf(x));           // col 15 = sin(x * 2^0)
      uint4* p = (uint4*)(hA + smp*ROWA);
      p[0] = make_uint4(d[0],d[1],d[2],d[3]);
      p[1] = make_uint4(d[4],d[5],d[6],d[7]);
    } else if(corner == 1){
      uint4* p = (uint4*)(hA + smp*ROWA + 80);   // cols 80..95 zero
      p[0] = make_uint4(0,0,0,0);
      p[1] = make_uint4(0,0,0,0);
    } else {
      int ray = ray_id[i];
      int cb = (corner - 2) * 16;
      unsigned int d[8];
      #pragma unroll
      for(int j = 0; j < 8; ++j){
        int c = cb + 2*j;
        float a = (c     < 27) ? ve[ray*27 + c]     : 0.f;
        float b = (c + 1 < 27) ? ve[ray*27 + c + 1] : 0.f;
        d[j] = packbf(a, b);
      }
      uint4* p = (uint4*)(hB + smp*ROWB + 128 + cb);
      p[0] = make_uint4(d[0],d[1],d[2],d[3]);
      p[1] = make_uint4(d[4],d[5],d[6],d[7]);
    }
  }

  // ---- phase 0b: posemb cols 16..79. 512 lanes = 128 samples x 4 chunks ------
  {
    int smp = tid & 127, chunk = 1 + (tid >> 7);   // 1..4
    int i2 = blk + smp;
    float x = xyz[3*i2+0], y = xyz[3*i2+1], z = xyz[3*i2+2];
    float vv[16];
    #pragma unroll
    for(int j = 0; j < 16; ++j){
      int c = chunk*16 + j;
      float r;
      if(c >= 75) r = 0.f;
      else {
        int q = (c < 45) ? (c-15) : (c-45);
        int ci = q/10, p = q - ci*10;
        float xv = (ci == 0) ? x : ((ci == 1) ? y : z);
        float a = xv * (float)(1 << p);
        r = (c < 45) ? __sinf(a) : __cosf(a);
      }
      vv[j] = r;
    }
    unsigned int d[8];
    #pragma unroll
    for(int j = 0; j < 8; ++j) d[j] = packbf(vv[2*j], vv[2*j+1]);
    uint4* p = (uint4*)(hA + smp*ROWA + chunk*16);
    p[0] = make_uint4(d[0],d[1],d[2],d[3]);
    p[1] = make_uint4(d[4],d[5],d[6],d[7]);
  }
  __syncthreads();

  int ln = lane & 31, kh = lane >> 5;
  layer32< 96, ROWA, ROWB>(hA, hB, wt0, b0, wave, ln, kh);  __syncthreads();
  layer32<128, ROWB, ROWA>(hB, hA, wt1, b1, wave, ln, kh);  __syncthreads();
  layer32<128, ROWA, ROWB>(hA, hB, wt2, b2, wave, ln, kh);  __syncthreads();

  // rgb head: 16x16x32 MFMA, K=160, 8 m-tiles = 8 waves
  {
    int col = lane & 15, q = lane >> 4;
    int mt = wave;
    f32x4 acc = {0.f, 0.f, 0.f, 0.f};
    const unsigned short* arow = hB + (mt*16 + col)*ROWB + q*8;
    const unsigned short* wrow = wtr + col*160 + q*8;
    #pragma unroll
    for(int ks = 0; ks < 5; ++ks){
      bf16x8 af = *(const bf16x8*)(arow + ks*32);
      bf16x8 bfr = *(const bf16x8*)(wrow + ks*32);
      acc = __builtin_amdgcn_mfma_f32_16x16x32_bf16(af, bfr, acc, 0, 0, 0);
    }
    if(col < 3){
      #pragma unroll
      for(int r = 0; r < 4; ++r){
        int sl = mt*16 + q*4 + r;
        float v = acc[r] + br[col];
        red[sl][col] = 1.f / (1.f + expf(-v));
      }
    }
  }
  __syncthreads();

  // coalesced rgba store (alpha in .w; composite happens in k_comp2)
  if(tid < SAMP){
    rgba_out[blk + tid] = make_float4(red[tid][0], red[tid][1], red[tid][2], red[tid][3]);
  }
}

// ---------------- per-ray: alpha scan + weighted composite in one pass ---------
__global__ __launch_bounds__(256) void k_comp2(const int* __restrict__ ray_id,
    const float4* __restrict__ rgba, float* __restrict__ out)
{
  int r = blockIdx.x*4 + (threadIdx.x >> 6);   // grid = NRAYS/4 blocks
  int lane = threadIdx.x & 63;
  int lo = 0, hi = M_SAMPLES;
  while(lo < hi){ int mid = (lo+hi) >> 1; if(ray_id[mid] < r) lo = mid+1; else hi = mid; }
  int s = lo;
  int lo2 = s, hi2 = M_SAMPLES;
  while(lo2 < hi2){ int mid = (lo2+hi2) >> 1; if(ray_id[mid] < r+1) lo2 = mid+1; else hi2 = mid; }
  int e = lo2;

  float carry = 1.f;
  float ar = 0.f, ag = 0.f, ab = 0.f;
  for(int base = s; base < e; base += 64){
    int idx = base + lane;
    float4 c = (idx < e) ? rgba[idx] : make_float4(0.f,0.f,0.f,0.f);
    float a = c.w;
    float incl = 1.f - a;
    #pragma unroll
    for(int d2 = 1; d2 < 64; d2 <<= 1){
      float t = __shfl_up(incl, d2);
      if(lane >= d2) incl *= t;
    }
    float excl = __shfl_up(incl, 1);
    if(lane == 0) excl = 1.f;
    float w = carry * excl * a;
    ar += w*c.x; ag += w*c.y; ab += w*c.z;
    carry *= __shfl(incl, 63);
  }
  #pragma unroll
  for(int m2 = 1; m2 < 64; m2 <<= 1){
    ar += __shfl_xor(ar, m2);
    ag += __shfl_xor(ag, m2);
    ab += __shfl_xor(ab, m2);
  }
  if(lane == 0){
    out[3*r+0] = ar + carry;
    out[3*r+1] = ag + carry;
    out[3*r+2] = ab + carry;
  }
}

// ---------------- host ----------------------------------------------------------
extern "C" void kernel_launch(void* const* d_in, const int* in_sizes, int n_in,
                              void* d_out, int out_size, void* d_ws, size_t ws_size,
                              hipStream_t stream)
{
  const float* xyz      = (const float*)d_in[0];
  const int*   ray_id   = (const int*)  d_in[1];
  const float* viewdirs = (const float*)d_in[2];
  const void*  mask     =               d_in[3];
  const float* density  = (const float*)d_in[4];
  const float* k0       = (const float*)d_in[5];
  const float* W0 = (const float*)d_in[6];  const float* b0 = (const float*)d_in[7];
  const float* W1 = (const float*)d_in[8];  const float* b1 = (const float*)d_in[9];
  const float* W2 = (const float*)d_in[10]; const float* b2 = (const float*)d_in[11];
  const float* Wr = (const float*)d_in[12]; const float* br = (const float*)d_in[13];
  float* out = (float*)d_out;

  char* ws = (char*)d_ws;
  size_t off = 0;
  auto take = [&](size_t nbytes) -> void* {
    void* p = ws + off;
    off = (off + nbytes + 255) & ~(size_t)255;
    return p;
  };
  int*            flag    = (int*)           take(4);
  unsigned short* wt0     = (unsigned short*)take(128*96*2);
  unsigned short* wt1     = (unsigned short*)take(128*128*2);
  unsigned short* wt2     = (unsigned short*)take(128*128*2);
  unsigned short* wtr     = (unsigned short*)take(16*160*2);
  float*          ve      = (float*)         take((size_t)NRAYS*27*4);
  float4*         rgba_ws = (float4*)        take((size_t)M_SAMPLES*16);
#ifdef HAVE_FP8
  uint4*          packed  = (uint4*)         take((size_t)NVOX*16);
#else
  uint4*          packed  = (uint4*)         take((size_t)NVOX*32);
#endif
  bool use_packed = (ws_size >= off);

  k_prep<<<NB_REPACK + 1 + NB_W + NB_VE, 256, 0, stream>>>(
      density, k0, packed, (const unsigned int*)mask, flag,
      W0, W1, W2, Wr, wt0, wt1, wt2, wtr, viewdirs, ve);
  if(use_packed){
    k_mlp<1><<<M_SAMPLES/SAMP, 512, 0, stream>>>(xyz, packed, density, k0, mask, flag,
                                                 ray_id, wt0, wt1, wt2, wtr,
                                                 b0, b1, b2, br, ve, rgba_ws);
  } else {
    k_mlp<0><<<M_SAMPLES/SAMP, 512, 0, stream>>>(xyz, packed, density, k0, mask, flag,
                                                 ray_id, wt0, wt1, wt2, wtr,
                                                 b0, b1, b2, br, ve, rgba_ws);
  }
  k_comp2<<<NRAYS/4, 256, 0, stream>>>(ray_id, rgba_ws, out);
}

// Round 11
// 434.145 us; speedup vs baseline: 1.4043x; 1.0017x over previous
//
#include <hip/hip_runtime.h>
#include <hip/hip_bf16.h>

#define M_SAMPLES 524288
#define NRAYS 8192
#define GXD 160
#define GYD 160
#define GZD 128
#define GYZ (GYD*GZD)
#define NVOX (GXD*GYD*GZD)
#define ACT_SHIFT -13.81550955796f
#define ROWA 136      // hA leading dim (shorts)
#define ROWB 136      // hB leading dim (shorts) — ve no longer staged
#define SAMP 128      // samples per k_mlp block

typedef __bf16 bf16x8 __attribute__((ext_vector_type(8)));
typedef float f32x4 __attribute__((ext_vector_type(4)));
typedef float f32x16 __attribute__((ext_vector_type(16)));
typedef float f32v2 __attribute__((ext_vector_type(2)));

static __device__ inline unsigned short f2bf(float f){
  __hip_bfloat16 h = __float2bfloat16(f);
  unsigned short u; __builtin_memcpy(&u, &h, 2); return u;
}
static __device__ inline float flo(unsigned int u){ return __uint_as_float(u << 16); }
static __device__ inline float fhi(unsigned int u){ return __uint_as_float(u & 0xffff0000u); }

#if defined(__has_builtin)
#if __has_builtin(__builtin_amdgcn_cvt_pk_bf16_f32)
#define HAVE_PK_BF16 1
#endif
#if __has_builtin(__builtin_amdgcn_cvt_pk_f32_fp8) && __has_builtin(__builtin_amdgcn_cvt_pk_fp8_f32)
#define HAVE_FP8 1
#endif
#endif

static __device__ inline unsigned int packbf(float a, float b){
#ifdef HAVE_PK_BF16
  typedef __bf16 bf16v2 __attribute__((ext_vector_type(2)));
  bf16v2 r = __builtin_amdgcn_cvt_pk_bf16_f32(a, b);
  unsigned int u; __builtin_memcpy(&u, &r, 4); return u;
#else
  return (unsigned int)f2bf(a) | ((unsigned int)f2bf(b) << 16);
#endif
}

struct Tri {
  int ix, iy, iz;
  float wx0, wx1, wy0, wy1, wz0, wz1;
};
static __device__ inline Tri tri_setup(float x, float y, float z){
  Tri t;
  float tx = (x+1.f)*0.5f*(float)(GXD-1); tx = fminf(fmaxf(tx,0.f),(float)(GXD-1));
  float ty = (y+1.f)*0.5f*(float)(GYD-1); ty = fminf(fmaxf(ty,0.f),(float)(GYD-1));
  float tz = (z+1.f)*0.5f*(float)(GZD-1); tz = fminf(fmaxf(tz,0.f),(float)(GZD-1));
  t.ix = min((int)tx, GXD-2); t.iy = min((int)ty, GYD-2); t.iz = min((int)tz, GZD-2);
  float fx = tx-t.ix, fy = ty-t.iy, fz = tz-t.iz;
  t.wx0 = 1.f-fx; t.wx1 = fx; t.wy0 = 1.f-fy; t.wy1 = fy; t.wz0 = 1.f-fz; t.wz1 = fz;
  return t;
}

// ---------------- merged prologue: repack | detect | weights | ray view-term ---
#define NB_REPACK (NVOX/256)              // 12800
#define NB_W      184                     // ceil(47104/256)
#define NB_RT     (NRAYS/256)             // 32
__global__ __launch_bounds__(256) void k_prep(
    const float* __restrict__ density, const float* __restrict__ k0,
    uint4* __restrict__ packed,
    const unsigned int* __restrict__ mw, int* __restrict__ flag,
    const float* __restrict__ W0, const float* __restrict__ W1,
    const float* __restrict__ W2, const float* __restrict__ Wr,
    const float* __restrict__ br,
    unsigned short* __restrict__ wt0, unsigned short* __restrict__ wt1,
    unsigned short* __restrict__ wt2, unsigned short* __restrict__ wtr,
    const float* __restrict__ vd, float* __restrict__ rayterm3)
{
  int b = blockIdx.x;
  if(b < NB_REPACK){
    int v = b*256 + threadIdx.x;
    const float4* kp = (const float4*)(k0 + (size_t)v*12);
    float4 a = kp[0], bb = kp[1], c = kp[2];
#ifdef HAVE_FP8
    uint4 o;
    o.x = __float_as_uint(density[v]);
    int w;
    w = __builtin_amdgcn_cvt_pk_fp8_f32(a.x, a.y, 0, false);
    w = __builtin_amdgcn_cvt_pk_fp8_f32(a.z, a.w, w, true);
    o.y = (unsigned int)w;
    w = __builtin_amdgcn_cvt_pk_fp8_f32(bb.x, bb.y, 0, false);
    w = __builtin_amdgcn_cvt_pk_fp8_f32(bb.z, bb.w, w, true);
    o.z = (unsigned int)w;
    w = __builtin_amdgcn_cvt_pk_fp8_f32(c.x, c.y, 0, false);
    w = __builtin_amdgcn_cvt_pk_fp8_f32(c.z, c.w, w, true);
    o.w = (unsigned int)w;
    packed[v] = o;
#else
    uint4 o0, o1;
    o0.x = __float_as_uint(density[v]);
    o0.y = packbf(a.x, a.y); o0.z = packbf(a.z, a.w); o0.w = packbf(bb.x, bb.y);
    o1.x = packbf(bb.z, bb.w); o1.y = packbf(c.x, c.y); o1.z = packbf(c.z, c.w);
    o1.w = 0;
    packed[(size_t)v*2]   = o0;
    packed[(size_t)v*2+1] = o1;
#endif
    return;
  }
  if(b == NB_REPACK){
    unsigned int v = mw[threadIdx.x & 63];
    unsigned long long any = __ballot(v > 1u);
    if(threadIdx.x == 0) *flag = (any != 0ull) ? 1 : 0;   // 1 = byte mask
    return;
  }
  if(b < NB_REPACK + 1 + NB_W){
    int t = (b - NB_REPACK - 1)*256 + threadIdx.x;
    if(t < 128*96){
      int n = t/96, k = t%96;
      wt0[t] = f2bf((k < 75) ? W0[k*128 + n] : 0.f);
    } else if(t < 128*96 + 16384){
      int j = t - 128*96; int n = j/128, k = j%128;
      wt1[j] = f2bf(W1[k*128 + n]);
    } else if(t < 128*96 + 32768){
      int j = t - 128*96 - 16384; int n = j/128, k = j%128;
      wt2[j] = f2bf(W2[k*128 + n]);
    } else if(t < 128*96 + 32768 + 16*128){
      int j = t - 128*96 - 32768; int n = j/128, k = j%128;
      wtr[j] = f2bf((n < 3) ? Wr[k*3 + n] : 0.f);
    }
    return;
  }
  // per-ray view term: rayterm3[ray][c] = br[c] + sum_j ve_j * Wr[(128+j)*3+c]
  int ray = (b - NB_REPACK - 1 - NB_W)*256 + threadIdx.x;
  if(ray >= NRAYS) return;
  float v0 = vd[ray*3+0], v1 = vd[ray*3+1], v2 = vd[ray*3+2];
  float vej[27];
  vej[0] = v0; vej[1] = v1; vej[2] = v2;
  #pragma unroll
  for(int ci = 0; ci < 3; ++ci){
    float xv = (ci == 0) ? v0 : ((ci == 1) ? v1 : v2);
    #pragma unroll
    for(int p = 0; p < 4; ++p){
      float arg = xv * (float)(1 << p);
      vej[3 + ci*4 + p]  = __sinf(arg);
      vej[15 + ci*4 + p] = __cosf(arg);
    }
  }
  float rt0 = br[0], rt1 = br[1], rt2 = br[2];
  #pragma unroll
  for(int j = 0; j < 27; ++j){
    const float* wr = Wr + (128 + j)*3;
    rt0 += vej[j]*wr[0]; rt1 += vej[j]*wr[1]; rt2 += vej[j]*wr[2];
  }
  rayterm3[ray*3+0] = rt0; rayterm3[ray*3+1] = rt1; rayterm3[ray*3+2] = rt2;
}

// ---------------- fused: gather+alpha + MLP + head -> per-sample rgba ----------
// 32x32x16 MFMA, A=weights B=activations -> D[neuron][sample].
template<int KDIM, int SROW, int DROW>
static __device__ inline void layer32(const unsigned short* src, unsigned short* dst,
    const unsigned short* __restrict__ wt, const float* __restrict__ bias,
    int wave, int ln, int kh)
{
  constexpr int NS = KDIM/16;
  int tile_n = wave >> 1;
  int m0 = (wave & 1) * 2;
  const unsigned short* wbase = wt + (tile_n*32 + ln)*KDIM + kh*8;
  const unsigned short* abase0 = src + ((m0  )*32 + ln)*SROW + kh*8;
  const unsigned short* abase1 = src + ((m0+1)*32 + ln)*SROW + kh*8;
  f32x16 acc0 = {0.f,0.f,0.f,0.f,0.f,0.f,0.f,0.f,0.f,0.f,0.f,0.f,0.f,0.f,0.f,0.f};
  f32x16 acc1 = acc0;
  #pragma unroll
  for(int st = 0; st < NS; ++st){
    bf16x8 wf = *(const bf16x8*)(wbase + st*16);
    bf16x8 a0 = *(const bf16x8*)(abase0 + st*16);
    bf16x8 a1 = *(const bf16x8*)(abase1 + st*16);
    acc0 = __builtin_amdgcn_mfma_f32_32x32x16_bf16(wf, a0, acc0, 0, 0, 0);
    acc1 = __builtin_amdgcn_mfma_f32_32x32x16_bf16(wf, a1, acc1, 0, 0, 0);
  }
  #pragma unroll
  for(int rep = 0; rep < 2; ++rep){
    const f32x16& acc = rep ? acc1 : acc0;
    int scol = (m0 + rep)*32 + ln;
    #pragma unroll
    for(int g = 0; g < 4; ++g){
      int n0 = tile_n*32 + g*8 + kh*4;
      float4 bv = *(const float4*)(bias + n0);
      unsigned int lo = packbf(fmaxf(acc[4*g+0] + bv.x, 0.f), fmaxf(acc[4*g+1] + bv.y, 0.f));
      unsigned int hi = packbf(fmaxf(acc[4*g+2] + bv.z, 0.f), fmaxf(acc[4*g+3] + bv.w, 0.f));
      unsigned long long o = (unsigned long long)lo | ((unsigned long long)hi << 32);
      *(unsigned long long*)(dst + scol*DROW + n0) = o;
    }
  }
}

template<int PACKED>
__global__ __launch_bounds__(512) void k_mlp(const float* __restrict__ xyz,
    const uint4* __restrict__ packed,
    const float* __restrict__ density, const float* __restrict__ k0,
    const void* __restrict__ mask, const int* __restrict__ flag,
    const int* __restrict__ ray_id,
    const unsigned short* __restrict__ wt0, const unsigned short* __restrict__ wt1,
    const unsigned short* __restrict__ wt2, const unsigned short* __restrict__ wtr,
    const float* __restrict__ b0, const float* __restrict__ b1,
    const float* __restrict__ b2,
    const float* __restrict__ rayterm3, float4* __restrict__ rgba_out)
{
  __shared__ alignas(16) unsigned short hA[SAMP*ROWA];
  __shared__ alignas(16) unsigned short hB[SAMP*ROWB];
  __shared__ float red[SAMP][4];
  __shared__ int ray_s[SAMP];

  int tid = threadIdx.x;
  int lane = tid & 63, wave = tid >> 6;
  int blk = blockIdx.x*SAMP;

  // ---- phase 0a: gather. 512 lanes = 128 samples x 4 corners (dz in-thread) --
  {
    int smp = tid >> 2, corner = tid & 3;
    int i = blk + smp;
    float x = xyz[3*i+0], y = xyz[3*i+1], z = xyz[3*i+2];
    Tri t = tri_setup(x, y, z);
    int dx = corner & 1, dy = corner >> 1;
    float wxy = (dx ? t.wx1 : t.wx0) * (dy ? t.wy1 : t.wy0);
    float w0 = wxy*t.wz0, w1 = wxy*t.wz1;
    size_t vox = (size_t)((t.ix+dx)*GYZ + (t.iy+dy)*GZD + t.iz);
    float pd;
    float pf[12];
#ifdef HAVE_FP8
    if(PACKED){
      uint4 q0 = packed[vox], q1 = packed[vox+1];
      pd = w0*__uint_as_float(q0.x) + w1*__uint_as_float(q1.x);
      f32v2 a, b;
      a = __builtin_amdgcn_cvt_pk_f32_fp8((int)q0.y, false);
      b = __builtin_amdgcn_cvt_pk_f32_fp8((int)q1.y, false);
      pf[0] = w0*a.x + w1*b.x;  pf[1] = w0*a.y + w1*b.y;
      a = __builtin_amdgcn_cvt_pk_f32_fp8((int)q0.y, true);
      b = __builtin_amdgcn_cvt_pk_f32_fp8((int)q1.y, true);
      pf[2] = w0*a.x + w1*b.x;  pf[3] = w0*a.y + w1*b.y;
      a = __builtin_amdgcn_cvt_pk_f32_fp8((int)q0.z, false);
      b = __builtin_amdgcn_cvt_pk_f32_fp8((int)q1.z, false);
      pf[4] = w0*a.x + w1*b.x;  pf[5] = w0*a.y + w1*b.y;
      a = __builtin_amdgcn_cvt_pk_f32_fp8((int)q0.z, true);
      b = __builtin_amdgcn_cvt_pk_f32_fp8((int)q1.z, true);
      pf[6] = w0*a.x + w1*b.x;  pf[7] = w0*a.y + w1*b.y;
      a = __builtin_amdgcn_cvt_pk_f32_fp8((int)q0.w, false);
      b = __builtin_amdgcn_cvt_pk_f32_fp8((int)q1.w, false);
      pf[8] = w0*a.x + w1*b.x;  pf[9] = w0*a.y + w1*b.y;
      a = __builtin_amdgcn_cvt_pk_f32_fp8((int)q0.w, true);
      b = __builtin_amdgcn_cvt_pk_f32_fp8((int)q1.w, true);
      pf[10]= w0*a.x + w1*b.x;  pf[11]= w0*a.y + w1*b.y;
    }
#else
    if(PACKED){
      const uint4* pv = packed + vox*2;
      uint4 q0 = pv[0], q1 = pv[1], q2 = pv[2], q3 = pv[3];
      pd = w0*__uint_as_float(q0.x) + w1*__uint_as_float(q2.x);
      pf[0]  = w0*flo(q0.y) + w1*flo(q2.y);  pf[1]  = w0*fhi(q0.y) + w1*fhi(q2.y);
      pf[2]  = w0*flo(q0.z) + w1*flo(q2.z);  pf[3]  = w0*fhi(q0.z) + w1*fhi(q2.z);
      pf[4]  = w0*flo(q0.w) + w1*flo(q2.w);  pf[5]  = w0*fhi(q0.w) + w1*fhi(q2.w);
      pf[6]  = w0*flo(q1.x) + w1*flo(q3.x);  pf[7]  = w0*fhi(q1.x) + w1*fhi(q3.x);
      pf[8]  = w0*flo(q1.y) + w1*flo(q3.y);  pf[9]  = w0*fhi(q1.y) + w1*fhi(q3.y);
      pf[10] = w0*flo(q1.z) + w1*flo(q3.z);  pf[11] = w0*fhi(q1.z) + w1*fhi(q3.z);
    }
#endif
    if(!PACKED){
      pd = w0*density[vox] + w1*density[vox+1];
      const float4* v = (const float4*)(k0 + vox*12);
      float4 a0 = v[0], a1 = v[1], a2 = v[2];
      float4 c0 = v[3], c1 = v[4], c2 = v[5];
      pf[0] = w0*a0.x + w1*c0.x;  pf[1] = w0*a0.y + w1*c0.y;
      pf[2] = w0*a0.z + w1*c0.z;  pf[3] = w0*a0.w + w1*c0.w;
      pf[4] = w0*a1.x + w1*c1.x;  pf[5] = w0*a1.y + w1*c1.y;
      pf[6] = w0*a1.z + w1*c1.z;  pf[7] = w0*a1.w + w1*c1.w;
      pf[8] = w0*a2.x + w1*c2.x;  pf[9] = w0*a2.y + w1*c2.y;
      pf[10]= w0*a2.z + w1*c2.z;  pf[11]= w0*a2.w + w1*c2.w;
    }
    #pragma unroll
    for(int m2 = 1; m2 < 4; m2 <<= 1){
      pd += __shfl_xor(pd, m2);
      #pragma unroll
      for(int j = 0; j < 12; ++j) pf[j] += __shfl_xor(pf[j], m2);
    }
    if(corner == 0){
      int mx = (int)rintf(x*79.5f + 79.5f); mx = min(max(mx,0), GXD-1);
      int my = (int)rintf(y*79.5f + 79.5f); my = min(max(my,0), GYD-1);
      int mz = (int)rintf(z*63.5f + 63.5f); mz = min(max(mz,0), GZD-1);
      int midx = mx*GYZ + my*GZD + mz;
      bool mm = (*flag) ? (((const unsigned char*)mask)[midx] != 0)
                        : (((const int*)mask)[midx] != 0);
      float e = expf(pd + ACT_SHIFT);
      float alpha = 1.f - rsqrtf(1.f + e);   // (1+e)^(-0.5), INTERVAL=0.5
      if(!mm) alpha = 0.f;
      red[smp][3] = alpha;                   // rides out in rgba.w
      unsigned int d[8];
      #pragma unroll
      for(int j = 0; j < 6; ++j) d[j] = packbf(pf[2*j], pf[2*j+1]);
      d[6] = packbf(x, y);
      d[7] = packbf(z, __sinf(x));           // col 15 = sin(x * 2^0)
      uint4* p = (uint4*)(hA + smp*ROWA);
      p[0] = make_uint4(d[0],d[1],d[2],d[3]);
      p[1] = make_uint4(d[4],d[5],d[6],d[7]);
    } else if(corner == 1){
      uint4* p = (uint4*)(hA + smp*ROWA + 80);   // cols 80..95 zero
      p[0] = make_uint4(0,0,0,0);
      p[1] = make_uint4(0,0,0,0);
      ray_s[smp] = ray_id[i];
    }
    // corners 2,3: gather + butterfly only
  }

  // ---- phase 0b: posemb cols 16..79. 512 lanes = 128 samples x 4 chunks ------
  {
    int smp = tid & 127, chunk = 1 + (tid >> 7);   // 1..4
    int i2 = blk + smp;
    float x = xyz[3*i2+0], y = xyz[3*i2+1], z = xyz[3*i2+2];
    float vv[16];
    #pragma unroll
    for(int j = 0; j < 16; ++j){
      int c = chunk*16 + j;
      float r;
      if(c >= 75) r = 0.f;
      else {
        int q = (c < 45) ? (c-15) : (c-45);
        int ci = q/10, p = q - ci*10;
        float xv = (ci == 0) ? x : ((ci == 1) ? y : z);
        float a = xv * (float)(1 << p);
        r = (c < 45) ? __sinf(a) : __cosf(a);
      }
      vv[j] = r;
    }
    unsigned int d[8];
    #pragma unroll
    for(int j = 0; j < 8; ++j) d[j] = packbf(vv[2*j], vv[2*j+1]);
    uint4* p = (uint4*)(hA + smp*ROWA + chunk*16);
    p[0] = make_uint4(d[0],d[1],d[2],d[3]);
    p[1] = make_uint4(d[4],d[5],d[6],d[7]);
  }
  __syncthreads();

  int ln = lane & 31, kh = lane >> 5;
  layer32< 96, ROWA, ROWB>(hA, hB, wt0, b0, wave, ln, kh);  __syncthreads();
  layer32<128, ROWB, ROWA>(hB, hA, wt1, b1, wave, ln, kh);  __syncthreads();
  layer32<128, ROWA, ROWB>(hA, hB, wt2, b2, wave, ln, kh);  __syncthreads();

  // rgb head: 16x16x32 MFMA, K=128, 8 m-tiles = 8 waves; + per-ray view term
  {
    int col = lane & 15, q = lane >> 4;
    int mt = wave;
    f32x4 acc = {0.f, 0.f, 0.f, 0.f};
    const unsigned short* arow = hB + (mt*16 + col)*ROWB + q*8;
    const unsigned short* wrow = wtr + col*128 + q*8;
    #pragma unroll
    for(int ks = 0; ks < 4; ++ks){
      bf16x8 af = *(const bf16x8*)(arow + ks*32);
      bf16x8 bfr = *(const bf16x8*)(wrow + ks*32);
      acc = __builtin_amdgcn_mfma_f32_16x16x32_bf16(af, bfr, acc, 0, 0, 0);
    }
    if(col < 3){
      #pragma unroll
      for(int r = 0; r < 4; ++r){
        int sl = mt*16 + q*4 + r;
        float v = acc[r] + rayterm3[ray_s[sl]*3 + col];
        red[sl][col] = 1.f / (1.f + expf(-v));
      }
    }
  }
  __syncthreads();

  // coalesced rgba store (alpha in .w; composite happens in k_comp2)
  if(tid < SAMP){
    rgba_out[blk + tid] = make_float4(red[tid][0], red[tid][1], red[tid][2], red[tid][3]);
  }
}

// ---------------- per-ray: alpha scan + weighted composite in one pass ---------
__global__ __launch_bounds__(256) void k_comp2(const int* __restrict__ ray_id,
    const float4* __restrict__ rgba, float* __restrict__ out)
{
  int r = blockIdx.x*4 + (threadIdx.x >> 6);   // grid = NRAYS/4 blocks
  int lane = threadIdx.x & 63;
  int lo = 0, hi = M_SAMPLES;
  while(lo < hi){ int mid = (lo+hi) >> 1; if(ray_id[mid] < r) lo = mid+1; else hi = mid; }
  int s = lo;
  int lo2 = s, hi2 = M_SAMPLES;
  while(lo2 < hi2){ int mid = (lo2+hi2) >> 1; if(ray_id[mid] < r+1) lo2 = mid+1; else hi2 = mid; }
  int e = lo2;

  float carry = 1.f;
  float ar = 0.f, ag = 0.f, ab = 0.f;
  for(int base = s; base < e; base += 64){
    int idx = base + lane;
    float4 c = (idx < e) ? rgba[idx] : make_float4(0.f,0.f,0.f,0.f);
    float a = c.w;
    float incl = 1.f - a;
    #pragma unroll
    for(int d2 = 1; d2 < 64; d2 <<= 1){
      float t = __shfl_up(incl, d2);
      if(lane >= d2) incl *= t;
    }
    float excl = __shfl_up(incl, 1);
    if(lane == 0) excl = 1.f;
    float w = carry * excl * a;
    ar += w*c.x; ag += w*c.y; ab += w*c.z;
    carry *= __shfl(incl, 63);
  }
  #pragma unroll
  for(int m2 = 1; m2 < 64; m2 <<= 1){
    ar += __shfl_xor(ar, m2);
    ag += __shfl_xor(ag, m2);
    ab += __shfl_xor(ab, m2);
  }
  if(lane == 0){
    out[3*r+0] = ar + carry;
    out[3*r+1] = ag + carry;
    out[3*r+2] = ab + carry;
  }
}

// ---------------- host ----------------------------------------------------------
extern "C" void kernel_launch(void* const* d_in, const int* in_sizes, int n_in,
                              void* d_out, int out_size, void* d_ws, size_t ws_size,
                              hipStream_t stream)
{
  const float* xyz      = (const float*)d_in[0];
  const int*   ray_id   = (const int*)  d_in[1];
  const float* viewdirs = (const float*)d_in[2];
  const void*  mask     =               d_in[3];
  const float* density  = (const float*)d_in[4];
  const float* k0       = (const float*)d_in[5];
  const float* W0 = (const float*)d_in[6];  const float* b0 = (const float*)d_in[7];
  const float* W1 = (const float*)d_in[8];  const float* b1 = (const float*)d_in[9];
  const float* W2 = (const float*)d_in[10]; const float* b2 = (const float*)d_in[11];
  const float* Wr = (const float*)d_in[12]; const float* br = (const float*)d_in[13];
  float* out = (float*)d_out;

  char* ws = (char*)d_ws;
  size_t off = 0;
  auto take = [&](size_t nbytes) -> void* {
    void* p = ws + off;
    off = (off + nbytes + 255) & ~(size_t)255;
    return p;
  };
  int*            flag     = (int*)           take(4);
  unsigned short* wt0      = (unsigned short*)take(128*96*2);
  unsigned short* wt1      = (unsigned short*)take(128*128*2);
  unsigned short* wt2      = (unsigned short*)take(128*128*2);
  unsigned short* wtr      = (unsigned short*)take(16*128*2);
  float*          rayterm3 = (float*)         take((size_t)NRAYS*3*4);
  float4*         rgba_ws  = (float4*)        take((size_t)M_SAMPLES*16);
#ifdef HAVE_FP8
  uint4*          packed   = (uint4*)         take((size_t)NVOX*16);
#else
  uint4*          packed   = (uint4*)         take((size_t)NVOX*32);
#endif
  bool use_packed = (ws_size >= off);

  k_prep<<<NB_REPACK + 1 + NB_W + NB_RT, 256, 0, stream>>>(
      density, k0, packed, (const unsigned int*)mask, flag,
      W0, W1, W2, Wr, br, wt0, wt1, wt2, wtr, viewdirs, rayterm3);
  if(use_packed){
    k_mlp<1><<<M_SAMPLES/SAMP, 512, 0, stream>>>(xyz, packed, density, k0, mask, flag,
                                                 ray_id, wt0, wt1, wt2, wtr,
                                                 b0, b1, b2, rayterm3, rgba_ws);
  } else {
    k_mlp<0><<<M_SAMPLES/SAMP, 512, 0, stream>>>(xyz, packed, density, k0, mask, flag,
                                                 ray_id, wt0, wt1, wt2, wtr,
                                                 b0, b1, b2, rayterm3, rgba_ws);
  }
  k_comp2<<<NRAYS/4, 256, 0, stream>>>(ray_id, rgba_ws, out);
}